// Round 3
// baseline (26732.364 us; speedup 1.0000x reference)
//
#include <hip/hip_runtime.h>
#include <hip/hip_bf16.h>
#include <math.h>

typedef __hip_bfloat16 bf16;

#define BB 16
#define PP 12
#define QQ 12
#define NN 2000
#define CC 1024

static __device__ __forceinline__ float ldf(float v) { return v; }
static __device__ __forceinline__ float ldf(bf16 v) { return __bfloat162float(v); }
static __device__ __forceinline__ void stf(float* p, float v) { *p = v; }
static __device__ __forceinline__ void stf(bf16* p, float v) { *p = __float2bfloat16(v); }

// convlstm weights (3,3,64,256) [ky][kx][ci][co] -> [(kk*256+co)*64+ci]
__global__ void k_conv_repack(float* __restrict__ dst, const float* __restrict__ src) {
  int i = blockIdx.x * 256 + threadIdx.x;
  if (i >= 9 * 64 * 256) return;
  int ci = i & 63;
  int co = (i >> 6) & 255;
  int kk = i >> 14;
  dst[i] = src[(kk * 64 + ci) * 256 + co];
}

// dcgru weights (512,O) row=f*4+k -> dst[(k*128+f)*O+o]
__global__ void k_gru_repack(float* __restrict__ dst, const float* __restrict__ src, int O) {
  int i = blockIdx.x * 256 + threadIdx.x;
  if (i >= 512 * O) return;
  int o = i % O;
  int f = (i / O) & 127;
  int k = i / (O * 128);
  dst[i] = src[(f * 4 + k) * O + o];
}

__global__ void k_dinv(const float* __restrict__ adj, float* __restrict__ dinv) {
  int row = blockIdx.x;
  float s = 0.f;
  for (int j = threadIdx.x; j < NN; j += 256) {
    float a = adj[(long long)row * NN + j];
    float at = adj[(long long)j * NN + row];
    s += fmaxf(a, at);
  }
  __shared__ float red[256];
  red[threadIdx.x] = s;
  __syncthreads();
  for (int st = 128; st > 0; st >>= 1) {
    if (threadIdx.x < st) red[threadIdx.x] += red[threadIdx.x + st];
    __syncthreads();
  }
  if (threadIdx.x == 0) {
    float d = red[0];
    dinv[row] = d > 0.f ? 1.0f / sqrtf(d) : 0.f;
  }
}

__global__ void k_L(const float* __restrict__ adj, const float* __restrict__ dinv,
                    float* __restrict__ Lf) {
  long long i = (long long)blockIdx.x * 256 + threadIdx.x;
  if (i >= (long long)NN * NN) return;
  int r = (int)(i / NN), c = (int)(i % NN);
  float a = fmaxf(adj[(long long)r * NN + c], adj[(long long)c * NN + r]);
  Lf[i] = -dinv[r] * a * dinv[c];
}

__global__ void k_gumbel_softmax(const float* __restrict__ ml, const float* __restrict__ gn,
                                 float* __restrict__ mZ) {
  int row = blockIdx.x;
  __shared__ float buf[CC];
  __shared__ float red[256];
  int t = threadIdx.x;
  float mx = -1e30f;
  for (int j = t; j < CC; j += 256) {
    float u = gn[(long long)row * CC + j];
    float g = -logf(-logf(u + 1e-20f) + 1e-20f);
    float v = ml[(long long)row * CC + j] + g;
    buf[j] = v;
    mx = fmaxf(mx, v);
  }
  red[t] = mx;
  __syncthreads();
  for (int st = 128; st > 0; st >>= 1) {
    if (t < st) red[t] = fmaxf(red[t], red[t + st]);
    __syncthreads();
  }
  mx = red[0];
  __syncthreads();
  float s = 0.f;
  for (int j = t; j < CC; j += 256) {
    float e = expf(buf[j] - mx);
    buf[j] = e;
    s += e;
  }
  red[t] = s;
  __syncthreads();
  for (int st = 128; st > 0; st >>= 1) {
    if (t < st) red[t] += red[t + st];
    __syncthreads();
  }
  float inv = 1.0f / red[0];
  for (int j = t; j < CC; j += 256) mZ[(long long)row * CC + j] = buf[j] * inv;
}

__global__ void k_te(const int* __restrict__ TE, const float* __restrict__ w1,
                     const float* __restrict__ b1, float* __restrict__ tmp) {
  int i = blockIdx.x * 256 + threadIdx.x;
  if (i >= BB * PP * 64) return;
  int j = i & 63;
  int bp = i >> 6;
  int b = bp / PP, p = bp % PP;
  int te0 = TE[(b * (PP + QQ) + p) * 2 + 0];
  int te1 = TE[(b * (PP + QQ) + p) * 2 + 1];
  float v = w1[te0 * 64 + j] + w1[(7 + te1) * 64 + j] + b1[j];
  tmp[i] = fmaxf(v, 0.f);
}

__global__ void k_zf1(const float* __restrict__ Z, const float* __restrict__ w1,
                      const float* __restrict__ b1, bf16* __restrict__ tmp) {
  long long i = (long long)blockIdx.x * 256 + threadIdx.x;
  if (i >= (long long)BB * PP * CC * 64) return;
  int j = (int)(i & 63);
  long long row = i >> 6;
  float z0 = Z[row * 2 + 0], z1 = Z[row * 2 + 1];
  float v = z0 * w1[j] + z1 * w1[64 + j] + b1[j];
  tmp[i] = __float2bfloat16(fmaxf(v, 0.f));
}

__global__ void k_add_stez(bf16* __restrict__ Zf, const float* __restrict__ seZ,
                           const float* __restrict__ teZ) {
  long long i = (long long)blockIdx.x * 256 + threadIdx.x;
  if (i >= (long long)BB * PP * CC * 64) return;
  int j = (int)(i & 63);
  long long row = i >> 6;
  int c = (int)(row % CC);
  int bp = (int)(row / CC);
  Zf[i] = __float2bfloat16(__bfloat162float(Zf[i]) + seZ[c * 64 + j] + teZ[bp * 64 + j]);
}

// ---------- generic GEMM: C = act(alpha*A@B + bias + beta*S) ----------
template <typename TA, typename TB, typename TC>
__global__ __launch_bounds__(256) void gemm_t(
    const TA* __restrict__ A, int lda, long long sA,
    const TB* __restrict__ Bm, int ldb, long long sB,
    TC* Cm, int ldc, long long sC,
    const TC* S, long long sS,
    const float* __restrict__ bias,
    int M, int Ncols, int K, float alpha, float beta, int act) {
  int bz = blockIdx.z;
  A += (long long)bz * sA;
  Bm += (long long)bz * sB;
  Cm += (long long)bz * sC;
  if (S) S += (long long)bz * sS;
  const int row0 = blockIdx.x * 64, col0 = blockIdx.y * 64;
  __shared__ float As[16][68];
  __shared__ float Bs[16][68];
  int tid = threadIdx.x, tx = tid & 15, ty = tid >> 4;
  float acc[4][4] = {};
  for (int k0 = 0; k0 < K; k0 += 16) {
#pragma unroll
    for (int j = 0; j < 4; ++j) {
      int e = tid + 256 * j;
      int m = e >> 4, kk = e & 15;
      int gm = row0 + m;
      As[kk][m] = (gm < M) ? ldf(A[(long long)gm * lda + k0 + kk]) : 0.f;
    }
#pragma unroll
    for (int j = 0; j < 4; ++j) {
      int e = tid + 256 * j;
      int kk = e >> 6, n = e & 63;
      int gn = col0 + n;
      Bs[kk][n] = (gn < Ncols) ? ldf(Bm[(long long)(k0 + kk) * ldb + gn]) : 0.f;
    }
    __syncthreads();
#pragma unroll
    for (int kk = 0; kk < 16; ++kk) {
      float a[4], bb[4];
#pragma unroll
      for (int i = 0; i < 4; ++i) a[i] = As[kk][ty * 4 + i];
#pragma unroll
      for (int j = 0; j < 4; ++j) bb[j] = Bs[kk][tx * 4 + j];
#pragma unroll
      for (int i = 0; i < 4; ++i)
#pragma unroll
        for (int j = 0; j < 4; ++j) acc[i][j] = fmaf(a[i], bb[j], acc[i][j]);
    }
    __syncthreads();
  }
#pragma unroll
  for (int i = 0; i < 4; ++i) {
    int r = row0 + ty * 4 + i;
    if (r >= M) continue;
#pragma unroll
    for (int j = 0; j < 4; ++j) {
      int cn = col0 + tx * 4 + j;
      if (cn >= Ncols) continue;
      float v = alpha * acc[i][j];
      if (bias) v += bias[cn];
      if (S) v += beta * ldf(S[(long long)r * ldc + cn]);
      if (act == 1) v = fmaxf(v, 0.f);
      else if (act == 2) v = 1.f / (1.f + expf(-v));
      else if (act == 3) v = tanhf(v);
      stf(&Cm[(long long)r * ldc + cn], v);
    }
  }
}

// ---------- ConvLSTM fused dual 3x3 conv ----------
__global__ __launch_bounds__(256) void k_clstm_conv(
    const bf16* __restrict__ Zf, const float* __restrict__ hprev,
    const float* __restrict__ wxp, const float* __restrict__ whp,
    bf16* __restrict__ gates, int p) {
  int y = blockIdx.x;
  int b = blockIdx.y;
  int co = threadIdx.x;
  __shared__ float sm[2][3][32][64];
  const bf16* xbase = Zf + ((long long)(b * PP + p)) * CC * 64;
  const float* hbase = hprev + (long long)b * CC * 64;
  for (int e = threadIdx.x; e < 2 * 3 * 32 * 64; e += 256) {
    int src = e / 6144;
    int rem = e % 6144;
    int ky = rem / 2048;
    int x = (rem >> 6) & 31;
    int ci = e & 63;
    int yy = y + ky - 1;
    float v = 0.f;
    if (yy >= 0 && yy < 32) {
      long long idx = ((long long)(yy * 32 + x)) * 64 + ci;
      v = src ? hbase[idx] : __bfloat162float(xbase[idx]);
    }
    sm[src][ky][x][ci] = v;
  }
  __syncthreads();
  float acc[32];
#pragma unroll
  for (int x = 0; x < 32; ++x) acc[x] = 0.f;
  for (int src = 0; src < 2; ++src) {
    const float* wp = src ? whp : wxp;
    for (int ky = 0; ky < 3; ++ky) {
#pragma unroll 1
      for (int ci4 = 0; ci4 < 16; ++ci4) {
        const float* wrow = wp + ((ky * 3 + 0) * 256 + co) * 64 + ci4 * 4;
        float4 w0 = *(const float4*)(wrow);
        float4 w1 = *(const float4*)(wrow + 256 * 64);
        float4 w2 = *(const float4*)(wrow + 2 * 256 * 64);
        float4 vm = make_float4(0.f, 0.f, 0.f, 0.f);
        float4 vc = *(const float4*)&sm[src][ky][0][ci4 * 4];
#pragma unroll
        for (int x = 0; x < 32; ++x) {
          float4 vp = (x < 31) ? *(const float4*)&sm[src][ky][x + 1][ci4 * 4]
                               : make_float4(0.f, 0.f, 0.f, 0.f);
          acc[x] += vm.x * w0.x + vm.y * w0.y + vm.z * w0.z + vm.w * w0.w +
                    vc.x * w1.x + vc.y * w1.y + vc.z * w1.z + vc.w * w1.w +
                    vp.x * w2.x + vp.y * w2.y + vp.z * w2.z + vp.w * w2.w;
          vm = vc;
          vc = vp;
        }
      }
    }
  }
  bf16* g = gates + (((long long)b * 32 + y) * 32) * 256 + co;
#pragma unroll 1
  for (int x = 0; x < 32; ++x) g[(long long)x * 256] = __float2bfloat16(acc[x]);
}

__global__ void k_clstm_update(const bf16* __restrict__ gates, float* __restrict__ c,
                               float* __restrict__ h, bf16* __restrict__ Zc, int p) {
  long long i = (long long)blockIdx.x * 256 + threadIdx.x;
  if (i >= (long long)BB * CC * 64) return;
  int d = (int)(i & 63);
  long long bc = i >> 6;
  int b = (int)(bc >> 10);
  int cell = (int)(bc & 1023);
  const bf16* g = gates + (((long long)b * CC) + cell) * 256;
  float gi = __bfloat162float(g[d]);
  float gf = __bfloat162float(g[64 + d]);
  float gg = __bfloat162float(g[128 + d]);
  float go = __bfloat162float(g[192 + d]);
  float hs_f = fminf(fmaxf(0.2f * gf + 0.5f, 0.f), 1.f);
  float hs_i = fminf(fmaxf(0.2f * gi + 0.5f, 0.f), 1.f);
  float hs_o = fminf(fmaxf(0.2f * go + 0.5f, 0.f), 1.f);
  float cv = hs_f * c[i] + hs_i * tanhf(gg);
  c[i] = cv;
  float hv = hs_o * tanhf(cv);
  h[i] = hv;
  Zc[(((long long)(b * PP + p)) * CC + cell) * 64 + d] = __float2bfloat16(hv);
}

// ---------- Xf = mlp2(X) + STEX + ZX (in place into ZX bf16) ----------
__global__ __launch_bounds__(256) void k_xf_build(
    const float* __restrict__ X, const float* __restrict__ w1, const float* __restrict__ b1,
    const float* __restrict__ w2, const float* __restrict__ b2v,
    const float* __restrict__ seX, const float* __restrict__ teX, bf16* Xf) {
  __shared__ float w2s[64][65];
  __shared__ float ts[4][64];
  int tid = threadIdx.x;
  for (int e = tid; e < 4096; e += 256) w2s[e >> 6][e & 63] = w2[e];
  long long row0 = (long long)blockIdx.x * 4;
  int r = tid >> 6, j = tid & 63;
  long long row = row0 + r;
  float t = 0.f;
  bool ok = row < (long long)BB * PP * NN;
  if (ok) {
    float x = X[row];
    t = fmaxf(x * w1[j] + b1[j], 0.f);
  }
  ts[r][j] = t;
  __syncthreads();
  if (ok) {
    float acc = 0.f;
#pragma unroll
    for (int kk = 0; kk < 64; ++kk) acc = fmaf(ts[r][kk], w2s[kk][j], acc);
    int n = (int)(row % NN);
    int bp = (int)(row / NN);
    long long o = row * 64 + j;
    Xf[o] = __float2bfloat16(__bfloat162float(Xf[o]) + acc + b2v[j] + seX[n * 64 + j] +
                             teX[bp * 64 + j]);
  }
}

__global__ void k_t0_gate(const bf16* __restrict__ Xf, const float* __restrict__ h,
                          float* __restrict__ T0, int p) {
  long long i = (long long)blockIdx.x * 256 + threadIdx.x;
  if (i >= (long long)BB * NN * 128) return;
  int f = (int)(i & 127);
  long long bn = i >> 7;
  int b = (int)(bn / NN);
  int n = (int)(bn % NN);
  float v = (f < 64) ? __bfloat162float(Xf[(((long long)(b * PP + p)) * NN + n) * 64 + f])
                     : h[bn * 64 + (f - 64)];
  T0[i] = v;
}

__global__ void k_t0_cand(const bf16* __restrict__ Xf, const float* __restrict__ h,
                          const float* __restrict__ ru, float* __restrict__ T0, int p) {
  long long i = (long long)blockIdx.x * 256 + threadIdx.x;
  if (i >= (long long)BB * NN * 128) return;
  int f = (int)(i & 127);
  long long bn = i >> 7;
  int b = (int)(bn / NN);
  int n = (int)(bn % NN);
  float v;
  if (f < 64) v = __bfloat162float(Xf[(((long long)(b * PP + p)) * NN + n) * 64 + f]);
  else v = ru[bn * 128 + (f - 64)] * h[bn * 64 + (f - 64)];
  T0[i] = v;
}

__global__ void k_h_update(float* __restrict__ h, const float* __restrict__ ru,
                           const float* __restrict__ cnd) {
  long long i = (long long)blockIdx.x * 256 + threadIdx.x;
  if (i >= (long long)BB * NN * 64) return;
  int d = (int)(i & 63);
  long long bn = i >> 6;
  float u = ru[bn * 128 + 64 + d];
  h[i] = u * h[i] + (1.f - u) * cnd[i];
}

__global__ void k_out(const float* __restrict__ Y, float* __restrict__ out) {
  int i = blockIdx.x * 256 + threadIdx.x;
  if (i >= BB * QQ * NN) return;
  int n = i % NN;
  int bq = i / NN;
  int b = bq / QQ, q = bq % QQ;
  out[i] = Y[((long long)b * NN + n) * 12 + q];
}

template <typename TA, typename TB, typename TC>
static void launch_gemm(hipStream_t stream, const TA* A, int lda, long long sA,
                        const TB* Bm, int ldb, long long sB, TC* Cm, int ldc, long long sC,
                        const TC* S, long long sS, const float* bias, int M, int Nc, int K,
                        float alpha, float beta, int act, int batch) {
  dim3 g((M + 63) / 64, (Nc + 63) / 64, batch);
  gemm_t<TA, TB, TC><<<g, dim3(256), 0, stream>>>(A, lda, sA, Bm, ldb, sB, Cm, ldc, sC, S,
                                                  sS, bias, M, Nc, K, alpha, beta, act);
}

extern "C" void kernel_launch(void* const* d_in, const int* in_sizes, int n_in,
                              void* d_out, int out_size, void* d_ws, size_t ws_size,
                              hipStream_t stream) {
  char* base = (char*)d_ws;
  size_t off = 0;
  auto alloc_bytes = [&](size_t nb) -> char* {
    char* p = base + off;
    off += (nb + 255) & ~(size_t)255;
    return p;
  };
  auto allocf = [&](size_t n) -> float* { return (float*)alloc_bytes(n * 4); };
  auto allocb = [&](size_t n) -> bf16* { return (bf16*)alloc_bytes(n * 2); };

  // fp32 inputs per reference dtypes; TE int32
  const float* X = (const float*)d_in[0];
  const float* Z = (const float*)d_in[1];
  const int* TE = (const int*)d_in[2];
  const float* adj_gg = (const float*)d_in[3];
  const float* adj_gr = (const float*)d_in[4];
  const float* gumbel = (const float*)d_in[5];
  const float* se_x = (const float*)d_in[6];
  const float* se_z = (const float*)d_in[7];
  const float* movement = (const float*)d_in[8];
  auto W = [&](int i) { return (const float*)d_in[i]; };

  // ---- allocations (pointer math only) ----
  float* wxp = allocf(147456);
  float* whp = allocf(147456);
  float* gwp = allocf(65536);
  float* cwp = allocf(32768);
  float* dinv = allocf(NN);
  float* Lf = allocf((size_t)NN * NN);
  float* mZ = allocf((size_t)CC * CC);
  float* seZ = allocf(CC * 64);
  float* teZ = allocf(BB * PP * 64);
  float* seX = allocf(NN * 64);
  float* teX = allocf(BB * PP * 64);
  float* mtmp = allocf(NN * 64);
  float* tetmp = allocf(BB * PP * 64);
  float* hg = allocf((size_t)BB * NN * 64);
  // pool: phase A {gates bf16 8.39M, chh f32 4.19M, ccc f32 4.19M}
  //       phase C {T0 f32 16.38M, T1 f32 16.38M, ru f32 16.38M, cnd f32 8.19M}
  char* pool = alloc_bytes(57344000);
  bf16* gates = (bf16*)pool;
  float* chh = (float*)(pool + 8388608);
  float* ccc = (float*)(pool + 12582912);
  float* T0 = (float*)pool;
  float* T1 = (float*)(pool + 16384000);
  float* ru = (float*)(pool + 32768000);
  float* cnd = (float*)(pool + 49152000);
  // zpool: Zf (B,P,C,64) aliased by ZX (B,P,N,64); Zc separate
  bf16* zpool = allocb((size_t)BB * PP * NN * 64);
  bf16* Zf = zpool;
  bf16* ZX = zpool;
  bf16* Zc = allocb((size_t)BB * PP * CC * 64);

  if (off > ws_size) return;  // soft-fail diagnostic instead of GPU fault

  // ---- precompute ----
  k_conv_repack<<<dim3(576), dim3(256), 0, stream>>>(wxp, W(39));
  k_conv_repack<<<dim3(576), dim3(256), 0, stream>>>(whp, W(40));
  k_gru_repack<<<dim3(256), dim3(256), 0, stream>>>(gwp, W(41), 128);
  k_gru_repack<<<dim3(128), dim3(256), 0, stream>>>(cwp, W(43), 64);
  k_dinv<<<dim3(NN), dim3(256), 0, stream>>>(adj_gg, dinv);
  k_L<<<dim3((NN * NN + 255) / 256), dim3(256), 0, stream>>>(adj_gg, dinv, Lf);
  k_gumbel_softmax<<<dim3(CC), dim3(256), 0, stream>>>(movement, gumbel, mZ);

  // ---- STEZ ----
  launch_gemm(stream, se_z, 64, 0LL, W(17), 64, 0LL, mtmp, 64, 0LL, (float*)nullptr, 0LL,
              W(18), CC, 64, 64, 1.f, 0.f, 1, 1);
  launch_gemm(stream, (const float*)mtmp, 64, 0LL, W(19), 64, 0LL, seZ, 64, 0LL,
              (float*)nullptr, 0LL, W(20), CC, 64, 64, 1.f, 0.f, 0, 1);
  k_te<<<dim3((BB * PP * 64 + 255) / 256), dim3(256), 0, stream>>>(TE, W(21), W(22), tetmp);
  launch_gemm(stream, (const float*)tetmp, 64, 0LL, W(23), 64, 0LL, teZ, 64, 0LL,
              (float*)nullptr, 0LL, W(24), BB * PP, 64, 64, 1.f, 0.f, 0, 1);

  // ---- Zf = mlp2(Z) + STEZ (Zc as layer-1 scratch) ----
  long long nZ = (long long)BB * PP * CC * 64;
  k_zf1<<<dim3((int)((nZ + 255) / 256)), dim3(256), 0, stream>>>(Z, W(25), W(26), Zc);
  launch_gemm(stream, (const bf16*)Zc, 64, 0LL, W(27), 64, 0LL, Zf, 64, 0LL,
              (bf16*)nullptr, 0LL, W(28), BB * PP * CC, 64, 64, 1.f, 0.f, 0, 1);
  k_add_stez<<<dim3((int)((nZ + 255) / 256)), dim3(256), 0, stream>>>(Zf, seZ, teZ);

  // ---- ConvLSTM ----
  hipMemsetAsync(chh, 0, (size_t)BB * CC * 64 * 4, stream);
  hipMemsetAsync(ccc, 0, (size_t)BB * CC * 64 * 4, stream);
  for (int p = 0; p < PP; ++p) {
    k_clstm_conv<<<dim3(32, BB), dim3(256), 0, stream>>>(Zf, chh, wxp, whp, gates, p);
    k_clstm_update<<<dim3((int)(((long long)BB * CC * 64 + 255) / 256)), dim3(256), 0,
                     stream>>>(gates, ccc, chh, Zc, p);
  }

  // ---- movement chain: Zf <- mZ@Zc ; Zc <- relu(Zf@W+b) ; ZX <- adj_gr@Zc ----
  launch_gemm(stream, (const float*)mZ, CC, 0LL, (const bf16*)Zc, 64, (long long)CC * 64,
              Zf, 64, (long long)CC * 64, (bf16*)nullptr, 0LL, (float*)nullptr, CC, 64, CC,
              1.f, 0.f, 0, BB * PP);
  launch_gemm(stream, (const bf16*)Zf, 64, 0LL, W(33), 64, 0LL, Zc, 64, 0LL,
              (bf16*)nullptr, 0LL, W(34), BB * PP * CC, 64, 64, 1.f, 0.f, 1, 1);
  launch_gemm(stream, adj_gr, CC, 0LL, (const bf16*)Zc, 64, (long long)CC * 64, ZX, 64,
              (long long)NN * 64, (bf16*)nullptr, 0LL, (float*)nullptr, NN, 64, CC, 1.f,
              0.f, 0, BB * PP);

  // ---- STEX ----
  launch_gemm(stream, se_x, 64, 0LL, W(9), 64, 0LL, mtmp, 64, 0LL, (float*)nullptr, 0LL,
              W(10), NN, 64, 64, 1.f, 0.f, 1, 1);
  launch_gemm(stream, (const float*)mtmp, 64, 0LL, W(11), 64, 0LL, seX, 64, 0LL,
              (float*)nullptr, 0LL, W(12), NN, 64, 64, 1.f, 0.f, 0, 1);
  k_te<<<dim3((BB * PP * 64 + 255) / 256), dim3(256), 0, stream>>>(TE, W(13), W(14), tetmp);
  launch_gemm(stream, (const float*)tetmp, 64, 0LL, W(15), 64, 0LL, teX, 64, 0LL,
              (float*)nullptr, 0LL, W(16), BB * PP, 64, 64, 1.f, 0.f, 0, 1);

  // ---- Xf (in place into ZX) ----
  k_xf_build<<<dim3(BB * PP * NN / 4), dim3(256), 0, stream>>>(X, W(29), W(30), W(31),
                                                               W(32), seX, teX, ZX);

  // ---- DCGRU ----
  hipMemsetAsync(hg, 0, (size_t)BB * NN * 64 * 4, stream);
  const long long sT = (long long)NN * 128;
  const long long nT = (long long)BB * NN * 128;
  for (int p = 0; p < PP; ++p) {
    // gate branch: ru = sigmoid(sum_k Tk @ Wg_k + bg)
    k_t0_gate<<<dim3((int)((nT + 255) / 256)), dim3(256), 0, stream>>>(ZX, hg, T0, p);
    launch_gemm(stream, (const float*)T0, 128, 0LL, (const float*)gwp, 128, 0LL, ru, 128,
                0LL, (float*)nullptr, 0LL, W(42), BB * NN, 128, 128, 1.f, 0.f, 0, 1);
    launch_gemm(stream, (const float*)Lf, NN, 0LL, (const float*)T0, 128, sT, T1, 128, sT,
                (float*)nullptr, 0LL, (float*)nullptr, NN, 128, NN, 1.f, 0.f, 0, BB);
    launch_gemm(stream, (const float*)T1, 128, 0LL, (const float*)(gwp + 16384), 128, 0LL,
                ru, 128, 0LL, (const float*)ru, 0LL, (float*)nullptr, BB * NN, 128, 128,
                1.f, 1.f, 0, 1);
    launch_gemm(stream, (const float*)Lf, NN, 0LL, (const float*)T1, 128, sT, T0, 128, sT,
                (const float*)T0, sT, (float*)nullptr, NN, 128, NN, 2.f, -1.f, 0, BB);
    launch_gemm(stream, (const float*)T0, 128, 0LL, (const float*)(gwp + 2 * 16384), 128,
                0LL, ru, 128, 0LL, (const float*)ru, 0LL, (float*)nullptr, BB * NN, 128,
                128, 1.f, 1.f, 0, 1);
    launch_gemm(stream, (const float*)Lf, NN, 0LL, (const float*)T0, 128, sT, T1, 128, sT,
                (const float*)T1, sT, (float*)nullptr, NN, 128, NN, 2.f, -1.f, 0, BB);
    launch_gemm(stream, (const float*)T1, 128, 0LL, (const float*)(gwp + 3 * 16384), 128,
                0LL, ru, 128, 0LL, (const float*)ru, 0LL, (float*)nullptr, BB * NN, 128,
                128, 1.f, 1.f, 2, 1);
    // candidate branch: cnd = tanh(sum_k Tk @ Wc_k + bc), with x,[r*h]
    k_t0_cand<<<dim3((int)((nT + 255) / 256)), dim3(256), 0, stream>>>(ZX, hg, ru, T0, p);
    launch_gemm(stream, (const float*)T0, 128, 0LL, (const float*)cwp, 64, 0LL, cnd, 64,
                0LL, (float*)nullptr, 0LL, W(44), BB * NN, 64, 128, 1.f, 0.f, 0, 1);
    launch_gemm(stream, (const float*)Lf, NN, 0LL, (const float*)T0, 128, sT, T1, 128, sT,
                (float*)nullptr, 0LL, (float*)nullptr, NN, 128, NN, 1.f, 0.f, 0, BB);
    launch_gemm(stream, (const float*)T1, 128, 0LL, (const float*)(cwp + 8192), 64, 0LL,
                cnd, 64, 0LL, (const float*)cnd, 0LL, (float*)nullptr, BB * NN, 64, 128,
                1.f, 1.f, 0, 1);
    launch_gemm(stream, (const float*)Lf, NN, 0LL, (const float*)T1, 128, sT, T0, 128, sT,
                (const float*)T0, sT, (float*)nullptr, NN, 128, NN, 2.f, -1.f, 0, BB);
    launch_gemm(stream, (const float*)T0, 128, 0LL, (const float*)(cwp + 2 * 8192), 64,
                0LL, cnd, 64, 0LL, (const float*)cnd, 0LL, (float*)nullptr, BB * NN, 64,
                128, 1.f, 1.f, 0, 1);
    launch_gemm(stream, (const float*)Lf, NN, 0LL, (const float*)T0, 128, sT, T1, 128, sT,
                (const float*)T1, sT, (float*)nullptr, NN, 128, NN, 2.f, -1.f, 0, BB);
    launch_gemm(stream, (const float*)T1, 128, 0LL, (const float*)(cwp + 3 * 8192), 64,
                0LL, cnd, 64, 0LL, (const float*)cnd, 0LL, (float*)nullptr, BB * NN, 64,
                128, 1.f, 1.f, 3, 1);
    k_h_update<<<dim3((int)(((long long)BB * NN * 64 + 255) / 256)), dim3(256), 0, stream>>>(
        hg, ru, cnd);
  }

  // ---- output head: T1 <- relu(hg@w1+b1); cnd <- T1@w2+b2; transpose ----
  launch_gemm(stream, (const float*)hg, 64, 0LL, W(35), 64, 0LL, T1, 64, 0LL,
              (float*)nullptr, 0LL, W(36), BB * NN, 64, 64, 1.f, 0.f, 1, 1);
  launch_gemm(stream, (const float*)T1, 64, 0LL, W(37), 12, 0LL, cnd, 12, 0LL,
              (float*)nullptr, 0LL, W(38), BB * NN, 12, 64, 1.f, 0.f, 0, 1);
  k_out<<<dim3((BB * QQ * NN + 255) / 256), dim3(256), 0, stream>>>(cnd, (float*)d_out);
}

// Round 4
// 11502.471 us; speedup vs baseline: 2.3241x; 2.3241x over previous
//
#include <hip/hip_runtime.h>
#include <hip/hip_bf16.h>
#include <math.h>

typedef _Float16 fp16;
typedef _Float16 f16x8 __attribute__((ext_vector_type(8)));
typedef float f32x4 __attribute__((ext_vector_type(4)));

#define BB 16
#define PP 12
#define QQ 12
#define NN 2000
#define CC 1024

static __device__ __forceinline__ float ldf(float v) { return v; }
static __device__ __forceinline__ float ldf(fp16 v) { return (float)v; }
static __device__ __forceinline__ void stf(float* p, float v) { *p = v; }
static __device__ __forceinline__ void stf(fp16* p, float v) { *p = (fp16)v; }

// ---------- conversions / repacks ----------
__global__ void k_f2h(fp16* __restrict__ dst, const float* __restrict__ src, long long n) {
  long long i = (long long)blockIdx.x * 256 + threadIdx.x;
  if (i < n) dst[i] = (fp16)src[i];
}

// convlstm weights (3,3,64,256) -> [(kk*256+co)*64+ci] fp32
__global__ void k_conv_repack(float* __restrict__ dst, const float* __restrict__ src) {
  int i = blockIdx.x * 256 + threadIdx.x;
  if (i >= 9 * 64 * 256) return;
  int ci = i & 63;
  int co = (i >> 6) & 255;
  int kk = i >> 14;
  dst[i] = src[(kk * 64 + ci) * 256 + co];
}

// dcgru weights (512,O) row=f*4+k -> dst[(k*128+f)*O+o] fp16
__global__ void k_gru_repack(fp16* __restrict__ dst, const float* __restrict__ src, int O) {
  int i = blockIdx.x * 256 + threadIdx.x;
  if (i >= 512 * O) return;
  int o = i % O;
  int f = (i / O) & 127;
  int k = i / (O * 128);
  dst[i] = (fp16)src[(f * 4 + k) * O + o];
}

// ---------- laplacian (writes fp16) ----------
__global__ void k_dinv(const float* __restrict__ adj, float* __restrict__ dinv) {
  int row = blockIdx.x;
  float s = 0.f;
  for (int j = threadIdx.x; j < NN; j += 256) {
    s += fmaxf(adj[(long long)row * NN + j], adj[(long long)j * NN + row]);
  }
  __shared__ float red[256];
  red[threadIdx.x] = s;
  __syncthreads();
  for (int st = 128; st > 0; st >>= 1) {
    if (threadIdx.x < st) red[threadIdx.x] += red[threadIdx.x + st];
    __syncthreads();
  }
  if (threadIdx.x == 0) {
    float d = red[0];
    dinv[row] = d > 0.f ? 1.0f / sqrtf(d) : 0.f;
  }
}

__global__ void k_L(const float* __restrict__ adj, const float* __restrict__ dinv,
                    fp16* __restrict__ Lh) {
  long long i = (long long)blockIdx.x * 256 + threadIdx.x;
  if (i >= (long long)NN * NN) return;
  int r = (int)(i / NN), c = (int)(i % NN);
  float a = fmaxf(adj[(long long)r * NN + c], adj[(long long)c * NN + r]);
  Lh[i] = (fp16)(-dinv[r] * a * dinv[c]);
}

// ---------- gumbel softmax -> fp16 ----------
__global__ void k_gumbel_softmax(const float* __restrict__ ml, const float* __restrict__ gn,
                                 fp16* __restrict__ mZ) {
  int row = blockIdx.x;
  __shared__ float buf[CC];
  __shared__ float red[256];
  int t = threadIdx.x;
  float mx = -1e30f;
  for (int j = t; j < CC; j += 256) {
    float u = gn[(long long)row * CC + j];
    float g = -logf(-logf(u + 1e-20f) + 1e-20f);
    float v = ml[(long long)row * CC + j] + g;
    buf[j] = v;
    mx = fmaxf(mx, v);
  }
  red[t] = mx;
  __syncthreads();
  for (int st = 128; st > 0; st >>= 1) {
    if (t < st) red[t] = fmaxf(red[t], red[t + st]);
    __syncthreads();
  }
  mx = red[0];
  __syncthreads();
  float s = 0.f;
  for (int j = t; j < CC; j += 256) {
    float e = expf(buf[j] - mx);
    buf[j] = e;
    s += e;
  }
  red[t] = s;
  __syncthreads();
  for (int st = 128; st > 0; st >>= 1) {
    if (t < st) red[t] += red[t + st];
    __syncthreads();
  }
  float inv = 1.0f / red[0];
  for (int j = t; j < CC; j += 256) mZ[(long long)row * CC + j] = (fp16)(buf[j] * inv);
}

__global__ void k_te(const int* __restrict__ TE, const float* __restrict__ w1,
                     const float* __restrict__ b1, float* __restrict__ tmp) {
  int i = blockIdx.x * 256 + threadIdx.x;
  if (i >= BB * PP * 64) return;
  int j = i & 63;
  int bp = i >> 6;
  int b = bp / PP, p = bp % PP;
  int te0 = TE[(b * (PP + QQ) + p) * 2 + 0];
  int te1 = TE[(b * (PP + QQ) + p) * 2 + 1];
  float v = w1[te0 * 64 + j] + w1[(7 + te1) * 64 + j] + b1[j];
  tmp[i] = fmaxf(v, 0.f);
}

__global__ void k_zf1(const float* __restrict__ Z, const float* __restrict__ w1,
                      const float* __restrict__ b1, fp16* __restrict__ tmp) {
  long long i = (long long)blockIdx.x * 256 + threadIdx.x;
  if (i >= (long long)BB * PP * CC * 64) return;
  int j = (int)(i & 63);
  long long row = i >> 6;
  float v = Z[row * 2 + 0] * w1[j] + Z[row * 2 + 1] * w1[64 + j] + b1[j];
  tmp[i] = (fp16)fmaxf(v, 0.f);
}

__global__ void k_add_stez(fp16* __restrict__ Zf, const float* __restrict__ seZ,
                           const float* __restrict__ teZ) {
  long long i = (long long)blockIdx.x * 256 + threadIdx.x;
  if (i >= (long long)BB * PP * CC * 64) return;
  int j = (int)(i & 63);
  long long row = i >> 6;
  int c = (int)(row % CC);
  int bp = (int)(row / CC);
  Zf[i] = (fp16)((float)Zf[i] + seZ[c * 64 + j] + teZ[bp * 64 + j]);
}

// ---------- generic fp32-path GEMM (small ops) ----------
template <typename TA, typename TB, typename TC>
__global__ __launch_bounds__(256) void gemm_t(
    const TA* __restrict__ A, int lda, long long sA,
    const TB* __restrict__ Bm, int ldb, long long sB,
    TC* Cm, int ldc, long long sC,
    const TC* S, long long sS,
    const float* __restrict__ bias,
    int M, int Ncols, int K, float alpha, float beta, int act) {
  int bz = blockIdx.z;
  A += (long long)bz * sA;
  Bm += (long long)bz * sB;
  Cm += (long long)bz * sC;
  if (S) S += (long long)bz * sS;
  const int row0 = blockIdx.x * 64, col0 = blockIdx.y * 64;
  __shared__ float As[16][68];
  __shared__ float Bs[16][68];
  int tid = threadIdx.x, tx = tid & 15, ty = tid >> 4;
  float acc[4][4] = {};
  for (int k0 = 0; k0 < K; k0 += 16) {
#pragma unroll
    for (int j = 0; j < 4; ++j) {
      int e = tid + 256 * j;
      int m = e >> 4, kk = e & 15;
      int gm = row0 + m;
      As[kk][m] = (gm < M) ? ldf(A[(long long)gm * lda + k0 + kk]) : 0.f;
    }
#pragma unroll
    for (int j = 0; j < 4; ++j) {
      int e = tid + 256 * j;
      int kk = e >> 6, n = e & 63;
      int gn = col0 + n;
      Bs[kk][n] = (gn < Ncols) ? ldf(Bm[(long long)(k0 + kk) * ldb + gn]) : 0.f;
    }
    __syncthreads();
#pragma unroll
    for (int kk = 0; kk < 16; ++kk) {
      float a[4], bb[4];
#pragma unroll
      for (int i = 0; i < 4; ++i) a[i] = As[kk][ty * 4 + i];
#pragma unroll
      for (int j = 0; j < 4; ++j) bb[j] = Bs[kk][tx * 4 + j];
#pragma unroll
      for (int i = 0; i < 4; ++i)
#pragma unroll
        for (int j = 0; j < 4; ++j) acc[i][j] = fmaf(a[i], bb[j], acc[i][j]);
    }
    __syncthreads();
  }
#pragma unroll
  for (int i = 0; i < 4; ++i) {
    int r = row0 + ty * 4 + i;
    if (r >= M) continue;
#pragma unroll
    for (int j = 0; j < 4; ++j) {
      int cn = col0 + tx * 4 + j;
      if (cn >= Ncols) continue;
      float v = alpha * acc[i][j];
      if (bias) v += bias[cn];
      if (S) v += beta * ldf(S[(long long)r * ldc + cn]);
      if (act == 1) v = fmaxf(v, 0.f);
      else if (act == 2) v = 1.f / (1.f + expf(-v));
      else if (act == 3) v = tanhf(v);
      stf(&Cm[(long long)r * ldc + cn], v);
    }
  }
}

// ---------- MFMA fp16 GEMM: C = act(alpha*A@B + bias + beta*S) ----------
// A[m, kc]: addr = A + (kc>>aShift)*aSlab + m*lda + cmap(kc&mask), cmap(c)=c+(c>=64?aHi:0)
// B[kc, n]: addr = B + z*bBatch + (kc>>bShift)*bSlab + (kc&mask)*ldb + n
template <typename TC>
__global__ __launch_bounds__(256) void mfma_gemm(
    const fp16* __restrict__ A, int lda, int aShift, long long aSlab, int aHi,
    const fp16* __restrict__ B, int ldb, long long bBatch, int bShift, long long bSlab,
    TC* __restrict__ C, int ldc, long long cBatch,
    const TC* __restrict__ S, float beta,
    const float* __restrict__ bias,
    int M, int Ncols, int K, float alpha, int act) {
  __shared__ fp16 As[128][40];  // [m][k], stride 40 halves -> 2-way bank alias only
  __shared__ fp16 Bs[64][40];   // [n][k] (transposed on stage)
  const int z = blockIdx.z;
  const int gm0 = blockIdx.x * 128, n0 = blockIdx.y * 64;
  B += (long long)z * bBatch;
  C += (long long)z * cBatch;
  if (S) S += (long long)z * cBatch;
  const int tid = threadIdx.x;
  const int lane = tid & 63, wv = tid >> 6;
  const int wr = wv >> 1, wc = wv & 1;
  const int quad = lane >> 4, ln = lane & 15;
  const unsigned aMask = (1u << aShift) - 1u;
  const unsigned bMask = (1u << bShift) - 1u;
  f32x4 acc[4][2];
#pragma unroll
  for (int i = 0; i < 4; ++i)
#pragma unroll
    for (int j = 0; j < 2; ++j) acc[i][j] = (f32x4){0.f, 0.f, 0.f, 0.f};

  for (int k0 = 0; k0 < K; k0 += 32) {
// stage A: 128 rows x 32 k
#pragma unroll
    for (int i = 0; i < 2; ++i) {
      int c = tid + 256 * i;
      int row = c >> 2, seg = c & 3;
      int gm = gm0 + row;
      int kk0 = k0 + seg * 8;
      int slab = (int)((unsigned)kk0 >> aShift);
      int kin = (int)((unsigned)kk0 & aMask);
      int ceff = kin + (kin >= 64 ? aHi : 0);
      const fp16* src = A + (long long)slab * aSlab + (long long)gm * lda + ceff;
      if (gm < M && kk0 + 8 <= K) {
        *(f16x8*)&As[row][seg * 8] = *(const f16x8*)src;
      } else {
#pragma unroll
        for (int j = 0; j < 8; ++j)
          As[row][seg * 8 + j] = (gm < M && kk0 + j < K) ? src[j] : (fp16)0.f;
      }
    }
    // stage B transposed into Bs[n][k]
    {
      int kk = k0 + (tid & 31);
      int ngrp = tid >> 5;
      int slab = (int)((unsigned)kk >> bShift);
      int kin = (int)((unsigned)kk & bMask);
      int n = n0 + ngrp * 8;
      const fp16* src = B + (long long)slab * bSlab + (long long)kin * ldb + n;
      if (kk < K && n + 8 <= Ncols) {
        f16x8 v = *(const f16x8*)src;
#pragma unroll
        for (int j = 0; j < 8; ++j) Bs[ngrp * 8 + j][tid & 31] = v[j];
      } else {
#pragma unroll
        for (int j = 0; j < 8; ++j)
          Bs[ngrp * 8 + j][tid & 31] = (kk < K && n + j < Ncols) ? src[j] : (fp16)0.f;
      }
    }
    __syncthreads();
    f16x8 af[4], bf[2];
#pragma unroll
    for (int wm = 0; wm < 4; ++wm)
      af[wm] = *(const f16x8*)&As[wr * 64 + wm * 16 + ln][quad * 8];
#pragma unroll
    for (int wn = 0; wn < 2; ++wn)
      bf[wn] = *(const f16x8*)&Bs[wc * 32 + wn * 16 + ln][quad * 8];
#pragma unroll
    for (int wm = 0; wm < 4; ++wm)
#pragma unroll
      for (int wn = 0; wn < 2; ++wn)
        acc[wm][wn] =
            __builtin_amdgcn_mfma_f32_16x16x32_f16(af[wm], bf[wn], acc[wm][wn], 0, 0, 0);
    __syncthreads();
  }
#pragma unroll
  for (int wm = 0; wm < 4; ++wm) {
#pragma unroll
    for (int wn = 0; wn < 2; ++wn) {
#pragma unroll
      for (int r = 0; r < 4; ++r) {
        int gm = gm0 + wr * 64 + wm * 16 + quad * 4 + r;
        int gn = n0 + wc * 32 + wn * 16 + ln;
        if (gm < M && gn < Ncols) {
          float v = alpha * acc[wm][wn][r];
          if (bias) v += bias[gn];
          if (S) v += beta * ldf(S[(long long)gm * ldc + gn]);
          if (act == 1) v = fmaxf(v, 0.f);
          else if (act == 2) v = 1.f / (1.f + expf(-v));
          else if (act == 3) v = tanhf(v);
          stf(&C[(long long)gm * ldc + gn], v);
        }
      }
    }
  }
}

// ---------- ConvLSTM fused dual 3x3 conv ----------
__global__ __launch_bounds__(256) void k_clstm_conv(
    const fp16* __restrict__ Zf, const float* __restrict__ hprev,
    const float* __restrict__ wxp, const float* __restrict__ whp,
    fp16* __restrict__ gates, int p) {
  int y = blockIdx.x;
  int b = blockIdx.y;
  int co = threadIdx.x;
  __shared__ float sm[2][3][32][64];
  const fp16* xbase = Zf + ((long long)(b * PP + p)) * CC * 64;
  const float* hbase = hprev + (long long)b * CC * 64;
  for (int e = threadIdx.x; e < 2 * 3 * 32 * 64; e += 256) {
    int src = e / 6144;
    int rem = e % 6144;
    int ky = rem / 2048;
    int x = (rem >> 6) & 31;
    int ci = e & 63;
    int yy = y + ky - 1;
    float v = 0.f;
    if (yy >= 0 && yy < 32) {
      long long idx = ((long long)(yy * 32 + x)) * 64 + ci;
      v = src ? hbase[idx] : (float)xbase[idx];
    }
    sm[src][ky][x][ci] = v;
  }
  __syncthreads();
  float acc[32];
#pragma unroll
  for (int x = 0; x < 32; ++x) acc[x] = 0.f;
  for (int src = 0; src < 2; ++src) {
    const float* wp = src ? whp : wxp;
    for (int ky = 0; ky < 3; ++ky) {
#pragma unroll 1
      for (int ci4 = 0; ci4 < 16; ++ci4) {
        const float* wrow = wp + ((ky * 3 + 0) * 256 + co) * 64 + ci4 * 4;
        float4 w0 = *(const float4*)(wrow);
        float4 w1 = *(const float4*)(wrow + 256 * 64);
        float4 w2 = *(const float4*)(wrow + 2 * 256 * 64);
        float4 vm = make_float4(0.f, 0.f, 0.f, 0.f);
        float4 vc = *(const float4*)&sm[src][ky][0][ci4 * 4];
#pragma unroll
        for (int x = 0; x < 32; ++x) {
          float4 vp = (x < 31) ? *(const float4*)&sm[src][ky][x + 1][ci4 * 4]
                               : make_float4(0.f, 0.f, 0.f, 0.f);
          acc[x] += vm.x * w0.x + vm.y * w0.y + vm.z * w0.z + vm.w * w0.w +
                    vc.x * w1.x + vc.y * w1.y + vc.z * w1.z + vc.w * w1.w +
                    vp.x * w2.x + vp.y * w2.y + vp.z * w2.z + vp.w * w2.w;
          vm = vc;
          vc = vp;
        }
      }
    }
  }
  fp16* g = gates + (((long long)b * 32 + y) * 32) * 256 + co;
#pragma unroll 1
  for (int x = 0; x < 32; ++x) g[(long long)x * 256] = (fp16)acc[x];
}

__global__ void k_clstm_update(const fp16* __restrict__ gates, float* __restrict__ c,
                               float* __restrict__ h, fp16* __restrict__ Zc, int p) {
  long long i = (long long)blockIdx.x * 256 + threadIdx.x;
  if (i >= (long long)BB * CC * 64) return;
  int d = (int)(i & 63);
  long long bc = i >> 6;
  int b = (int)(bc >> 10);
  int cell = (int)(bc & 1023);
  const fp16* g = gates + (((long long)b * CC) + cell) * 256;
  float gi = (float)g[d], gf = (float)g[64 + d], gg = (float)g[128 + d],
        go = (float)g[192 + d];
  float hs_f = fminf(fmaxf(0.2f * gf + 0.5f, 0.f), 1.f);
  float hs_i = fminf(fmaxf(0.2f * gi + 0.5f, 0.f), 1.f);
  float hs_o = fminf(fmaxf(0.2f * go + 0.5f, 0.f), 1.f);
  float cv = hs_f * c[i] + hs_i * tanhf(gg);
  c[i] = cv;
  float hv = hs_o * tanhf(cv);
  h[i] = hv;
  Zc[(((long long)(b * PP + p)) * CC + cell) * 64 + d] = (fp16)hv;
}

// ---------- Xf = mlp2(X) + STEX + ZX (in place into ZX fp16) ----------
__global__ __launch_bounds__(256) void k_xf_build(
    const float* __restrict__ X, const float* __restrict__ w1, const float* __restrict__ b1,
    const float* __restrict__ w2, const float* __restrict__ b2v,
    const float* __restrict__ seX, const float* __restrict__ teX, fp16* Xf) {
  __shared__ float w2s[64][65];
  __shared__ float ts[4][64];
  int tid = threadIdx.x;
  for (int e = tid; e < 4096; e += 256) w2s[e >> 6][e & 63] = w2[e];
  long long row0 = (long long)blockIdx.x * 4;
  int r = tid >> 6, j = tid & 63;
  long long row = row0 + r;
  float t = 0.f;
  bool ok = row < (long long)BB * PP * NN;
  if (ok) t = fmaxf(X[row] * w1[j] + b1[j], 0.f);
  ts[r][j] = t;
  __syncthreads();
  if (ok) {
    float acc = 0.f;
#pragma unroll
    for (int kk = 0; kk < 64; ++kk) acc = fmaf(ts[r][kk], w2s[kk][j], acc);
    int n = (int)(row % NN);
    int bp = (int)(row / NN);
    long long o = row * 64 + j;
    Xf[o] = (fp16)((float)Xf[o] + acc + b2v[j] + seX[n * 64 + j] + teX[bp * 64 + j]);
  }
}

// ---------- DCGRU builders ----------
__global__ void k_u0_gate(const fp16* __restrict__ ZX, const float* __restrict__ hg,
                          fp16* __restrict__ U0, int p) {
  long long i = (long long)blockIdx.x * 256 + threadIdx.x;
  if (i >= (long long)BB * NN * 128) return;
  int d = (int)(i & 127);
  long long row = i >> 7;
  int b = (int)(row / NN);
  int n = (int)(row % NN);
  float v = (d < 64) ? (float)ZX[(((long long)(b * PP + p)) * NN + n) * 64 + d]
                     : hg[row * 64 + (d - 64)];
  U0[row * 192 + d] = (fp16)v;
}

__global__ void k_u0_cand(const float* __restrict__ ru, const float* __restrict__ hg,
                          fp16* __restrict__ U0) {
  long long i = (long long)blockIdx.x * 256 + threadIdx.x;
  if (i >= (long long)BB * NN * 64) return;
  int d = (int)(i & 63);
  long long row = i >> 6;
  U0[row * 192 + 128 + d] = (fp16)(ru[row * 128 + d] * hg[row * 64 + d]);
}

__global__ void k_h_update(float* __restrict__ h, const float* __restrict__ ru,
                           const float* __restrict__ cnd) {
  long long i = (long long)blockIdx.x * 256 + threadIdx.x;
  if (i >= (long long)BB * NN * 64) return;
  int d = (int)(i & 63);
  long long bn = i >> 6;
  float u = ru[bn * 128 + 64 + d];
  h[i] = u * h[i] + (1.f - u) * cnd[i];
}

__global__ void k_out(const float* __restrict__ Y, float* __restrict__ out) {
  int i = blockIdx.x * 256 + threadIdx.x;
  if (i >= BB * QQ * NN) return;
  int n = i % NN;
  int bq = i / NN;
  int b = bq / QQ, q = bq % QQ;
  out[i] = Y[((long long)b * NN + n) * 12 + q];
}

// ---------- host helpers ----------
template <typename TA, typename TB, typename TC>
static void launch_gemm(hipStream_t stream, const TA* A, int lda, long long sA,
                        const TB* Bm, int ldb, long long sB, TC* Cm, int ldc, long long sC,
                        const TC* S, long long sS, const float* bias, int M, int Nc, int K,
                        float alpha, float beta, int act, int batch) {
  dim3 g((M + 63) / 64, (Nc + 63) / 64, batch);
  gemm_t<TA, TB, TC><<<g, dim3(256), 0, stream>>>(A, lda, sA, Bm, ldb, sB, Cm, ldc, sC, S,
                                                  sS, bias, M, Nc, K, alpha, beta, act);
}

template <typename TC>
static void launch_mfma(hipStream_t stream, const fp16* A, int lda, int aShift,
                        long long aSlab, int aHi, const fp16* B, int ldb, long long bBatch,
                        int bShift, long long bSlab, TC* C, int ldc, long long cBatch,
                        const TC* S, float beta, const float* bias, int M, int Nc, int K,
                        float alpha, int act, int batch) {
  dim3 g((M + 127) / 128, (Nc + 63) / 64, batch);
  mfma_gemm<TC><<<g, dim3(256), 0, stream>>>(A, lda, aShift, aSlab, aHi, B, ldb, bBatch,
                                             bShift, bSlab, C, ldc, cBatch, S, beta, bias,
                                             M, Nc, K, alpha, act);
}

extern "C" void kernel_launch(void* const* d_in, const int* in_sizes, int n_in,
                              void* d_out, int out_size, void* d_ws, size_t ws_size,
                              hipStream_t stream) {
  char* base = (char*)d_ws;
  size_t off = 0;
  auto alloc_bytes = [&](size_t nb) -> char* {
    char* p = base + off;
    off += (nb + 255) & ~(size_t)255;
    return p;
  };
  auto allocf = [&](size_t n) -> float* { return (float*)alloc_bytes(n * 4); };
  auto alloch = [&](size_t n) -> fp16* { return (fp16*)alloc_bytes(n * 2); };

  const float* X = (const float*)d_in[0];
  const float* Z = (const float*)d_in[1];
  const int* TE = (const int*)d_in[2];
  const float* adj_gg = (const float*)d_in[3];
  const float* adj_gr = (const float*)d_in[4];
  const float* gumbel = (const float*)d_in[5];
  const float* se_x = (const float*)d_in[6];
  const float* se_z = (const float*)d_in[7];
  const float* movement = (const float*)d_in[8];
  auto W = [&](int i) { return (const float*)d_in[i]; };

  // ---- allocations ----
  float* wxp = allocf(147456);
  float* whp = allocf(147456);
  fp16* gwh = alloch(65536);   // [4][128][128]
  fp16* cwh = alloch(32768);   // [4][128][64]
  float* dinv = allocf(NN);
  fp16* Lh = alloch((size_t)NN * NN);
  fp16* mZh = alloch((size_t)CC * CC);
  fp16* agh = alloch((size_t)NN * CC);
  float* seZ = allocf(CC * 64);
  float* teZ = allocf(BB * PP * 64);
  float* seX = allocf(NN * 64);
  float* teX = allocf(BB * PP * 64);
  float* mtmp = allocf(NN * 64);
  float* tetmp = allocf(BB * PP * 64);
  float* hg = allocf((size_t)BB * NN * 64);
  float* ru = allocf((size_t)BB * NN * 128);
  float* cnd = allocf((size_t)BB * NN * 64);
  // U slabs: 4 x [16][2000][192] fp16; ConvLSTM {gates,chh,ccc} aliased inside
  const long long SLAB = (long long)BB * NN * 192;  // 6,144,000 elements
  fp16* Uall = alloch((size_t)4 * SLAB);
  fp16* gates = (fp16*)Uall;
  float* chh = (float*)((char*)Uall + 8388608);
  float* ccc = (float*)((char*)Uall + 12582912);
  // zpool: Zf (B,P,C,64) aliased by ZX (B,P,N,64); Zc separate
  fp16* zpool = alloch((size_t)BB * PP * NN * 64);
  fp16* Zf = zpool;
  fp16* ZX = zpool;
  fp16* Zc = alloch((size_t)BB * PP * CC * 64);

  if (off > ws_size) return;  // soft-fail diagnostic

  // ---- precompute ----
  k_conv_repack<<<dim3(576), dim3(256), 0, stream>>>(wxp, W(39));
  k_conv_repack<<<dim3(576), dim3(256), 0, stream>>>(whp, W(40));
  k_gru_repack<<<dim3(256), dim3(256), 0, stream>>>(gwh, W(41), 128);
  k_gru_repack<<<dim3(128), dim3(256), 0, stream>>>(cwh, W(43), 64);
  k_dinv<<<dim3(NN), dim3(256), 0, stream>>>(adj_gg, dinv);
  k_L<<<dim3((NN * NN + 255) / 256), dim3(256), 0, stream>>>(adj_gg, dinv, Lh);
  k_gumbel_softmax<<<dim3(CC), dim3(256), 0, stream>>>(movement, gumbel, mZh);
  k_f2h<<<dim3((NN * CC + 255) / 256), dim3(256), 0, stream>>>(agh, adj_gr, (long long)NN * CC);

  // ---- STEZ ----
  launch_gemm(stream, se_z, 64, 0LL, W(17), 64, 0LL, mtmp, 64, 0LL, (float*)nullptr, 0LL,
              W(18), CC, 64, 64, 1.f, 0.f, 1, 1);
  launch_gemm(stream, (const float*)mtmp, 64, 0LL, W(19), 64, 0LL, seZ, 64, 0LL,
              (float*)nullptr, 0LL, W(20), CC, 64, 64, 1.f, 0.f, 0, 1);
  k_te<<<dim3((BB * PP * 64 + 255) / 256), dim3(256), 0, stream>>>(TE, W(21), W(22), tetmp);
  launch_gemm(stream, (const float*)tetmp, 64, 0LL, W(23), 64, 0LL, teZ, 64, 0LL,
              (float*)nullptr, 0LL, W(24), BB * PP, 64, 64, 1.f, 0.f, 0, 1);

  // ---- Zf = mlp2(Z) + STEZ (Zc as layer-1 scratch) ----
  long long nZ = (long long)BB * PP * CC * 64;
  k_zf1<<<dim3((int)((nZ + 255) / 256)), dim3(256), 0, stream>>>(Z, W(25), W(26), Zc);
  launch_gemm(stream, (const fp16*)Zc, 64, 0LL, W(27), 64, 0LL, Zf, 64, 0LL,
              (fp16*)nullptr, 0LL, W(28), BB * PP * CC, 64, 64, 1.f, 0.f, 0, 1);
  k_add_stez<<<dim3((int)((nZ + 255) / 256)), dim3(256), 0, stream>>>(Zf, seZ, teZ);

  // ---- ConvLSTM ----
  hipMemsetAsync(chh, 0, (size_t)BB * CC * 64 * 4, stream);
  hipMemsetAsync(ccc, 0, (size_t)BB * CC * 64 * 4, stream);
  for (int p = 0; p < PP; ++p) {
    k_clstm_conv<<<dim3(32, BB), dim3(256), 0, stream>>>(Zf, chh, wxp, whp, gates, p);
    k_clstm_update<<<dim3((int)(((long long)BB * CC * 64 + 255) / 256)), dim3(256), 0,
                     stream>>>(gates, ccc, chh, Zc, p);
  }

  // ---- movement chain: Zf <- mZ@Zc ; Zc <- relu(Zf@W+b) ; ZX <- adj_gr@Zc ----
  launch_mfma<fp16>(stream, mZh, CC, 31, 0LL, 0, (const fp16*)Zc, 64, (long long)CC * 64,
                    31, 0LL, Zf, 64, (long long)CC * 64, (const fp16*)nullptr, 0.f, nullptr,
                    CC, 64, CC, 1.f, 0, BB * PP);
  launch_gemm(stream, (const fp16*)Zf, 64, 0LL, W(33), 64, 0LL, Zc, 64, 0LL,
              (fp16*)nullptr, 0LL, W(34), BB * PP * CC, 64, 64, 1.f, 0.f, 1, 1);
  launch_mfma<fp16>(stream, agh, CC, 31, 0LL, 0, (const fp16*)Zc, 64, (long long)CC * 64,
                    31, 0LL, ZX, 64, (long long)NN * 64, (const fp16*)nullptr, 0.f, nullptr,
                    NN, 64, CC, 1.f, 0, BB * PP);

  // ---- STEX ----
  launch_gemm(stream, se_x, 64, 0LL, W(9), 64, 0LL, mtmp, 64, 0LL, (float*)nullptr, 0LL,
              W(10), NN, 64, 64, 1.f, 0.f, 1, 1);
  launch_gemm(stream, (const float*)mtmp, 64, 0LL, W(11), 64, 0LL, seX, 64, 0LL,
              (float*)nullptr, 0LL, W(12), NN, 64, 64, 1.f, 0.f, 0, 1);
  k_te<<<dim3((BB * PP * 64 + 255) / 256), dim3(256), 0, stream>>>(TE, W(13), W(14), tetmp);
  launch_gemm(stream, (const float*)tetmp, 64, 0LL, W(15), 64, 0LL, teX, 64, 0LL,
              (float*)nullptr, 0LL, W(16), BB * PP, 64, 64, 1.f, 0.f, 0, 1);

  // ---- Xf (in place into ZX) ----
  k_xf_build<<<dim3(BB * PP * NN / 4), dim3(256), 0, stream>>>(X, W(29), W(30), W(31),
                                                               W(32), seX, teX, ZX);

  // ---- DCGRU ----
  hipMemsetAsync(hg, 0, (size_t)BB * NN * 64 * 4, stream);
  const long long bStr = (long long)NN * 192;  // per-batch stride within a U slab
  fp16* U0 = Uall;
  fp16* U1 = Uall + SLAB;
  fp16* U2 = Uall + 2 * SLAB;
  fp16* U3 = Uall + 3 * SLAB;
  const long long n128 = (long long)BB * NN * 128;
  const long long n64 = (long long)BB * NN * 64;
  for (int p = 0; p < PP; ++p) {
    // gate chain on cols 0..127 = [x | h]
    k_u0_gate<<<dim3((int)((n128 + 255) / 256)), dim3(256), 0, stream>>>(ZX, hg, U0, p);
    launch_mfma<fp16>(stream, Lh, NN, 31, 0LL, 0, U0, 192, bStr, 31, 0LL, U1, 192, bStr,
                      (const fp16*)nullptr, 0.f, nullptr, NN, 128, NN, 1.f, 0, BB);
    launch_mfma<fp16>(stream, Lh, NN, 31, 0LL, 0, U1, 192, bStr, 31, 0LL, U2, 192, bStr,
                      (const fp16*)U0, -1.f, nullptr, NN, 128, NN, 2.f, 0, BB);
    launch_mfma<fp16>(stream, Lh, NN, 31, 0LL, 0, U2, 192, bStr, 31, 0LL, U3, 192, bStr,
                      (const fp16*)U1, -1.f, nullptr, NN, 128, NN, 2.f, 0, BB);
    // ru = sigmoid([U0..U3] @ gw + bg), K=512 via slab addressing
    launch_mfma<float>(stream, Uall, 192, 7, SLAB, 0, gwh, 128, 0LL, 7, 16384LL, ru, 128,
                       0LL, (const float*)nullptr, 0.f, W(42), BB * NN, 128, 512, 1.f, 2, 1);
    // cand chain on cols 128..191 = r*h (x-half reused from gate chain)
    k_u0_cand<<<dim3((int)((n64 + 255) / 256)), dim3(256), 0, stream>>>(ru, hg, U0);
    launch_mfma<fp16>(stream, Lh, NN, 31, 0LL, 0, U0 + 128, 192, bStr, 31, 0LL, U1 + 128,
                      192, bStr, (const fp16*)nullptr, 0.f, nullptr, NN, 64, NN, 1.f, 0, BB);
    launch_mfma<fp16>(stream, Lh, NN, 31, 0LL, 0, U1 + 128, 192, bStr, 31, 0LL, U2 + 128,
                      192, bStr, (const fp16*)(U0 + 128), -1.f, nullptr, NN, 64, NN, 2.f, 0,
                      BB);
    launch_mfma<fp16>(stream, Lh, NN, 31, 0LL, 0, U2 + 128, 192, bStr, 31, 0LL, U3 + 128,
                      192, bStr, (const fp16*)(U1 + 128), -1.f, nullptr, NN, 64, NN, 2.f, 0,
                      BB);
    // cnd = tanh([x-cheb | rh-cheb] @ cw + bc): cmap c>=64 -> col c+64
    launch_mfma<float>(stream, Uall, 192, 7, SLAB, 64, cwh, 64, 0LL, 7, 8192LL, cnd, 64,
                       0LL, (const float*)nullptr, 0.f, W(44), BB * NN, 64, 512, 1.f, 3, 1);
    k_h_update<<<dim3((int)((n64 + 255) / 256)), dim3(256), 0, stream>>>(hg, ru, cnd);
  }

  // ---- output head: ru[:,:64] <- relu(hg@w1+b1); cnd <- @w2+b2; transpose ----
  launch_gemm(stream, (const float*)hg, 64, 0LL, W(35), 64, 0LL, ru, 64, 0LL,
              (float*)nullptr, 0LL, W(36), BB * NN, 64, 64, 1.f, 0.f, 1, 1);
  launch_gemm(stream, (const float*)ru, 64, 0LL, W(37), 12, 0LL, cnd, 12, 0LL,
              (float*)nullptr, 0LL, W(38), BB * NN, 12, 64, 1.f, 0.f, 0, 1);
  k_out<<<dim3((BB * QQ * NN + 255) / 256), dim3(256), 0, stream>>>(cnd, (float*)d_out);
}

// Round 5
// 8659.048 us; speedup vs baseline: 3.0872x; 1.3284x over previous
//
#include <hip/hip_runtime.h>
#include <hip/hip_bf16.h>
#include <math.h>

typedef _Float16 fp16;
typedef _Float16 f16x8 __attribute__((ext_vector_type(8)));
typedef float f32x4 __attribute__((ext_vector_type(4)));

#define BB 16
#define PP 12
#define QQ 12
#define NN 2000
#define CC 1024

static __device__ __forceinline__ float ldf(float v) { return v; }
static __device__ __forceinline__ float ldf(fp16 v) { return (float)v; }
static __device__ __forceinline__ void stf(float* p, float v) { *p = v; }
static __device__ __forceinline__ void stf(fp16* p, float v) { *p = (fp16)v; }

// ---------- conversions / repacks ----------
__global__ void k_f2h(fp16* __restrict__ dst, const float* __restrict__ src, long long n) {
  long long i = (long long)blockIdx.x * 256 + threadIdx.x;
  if (i < n) dst[i] = (fp16)src[i];
}

// dcgru weights (512,O) row=f*4+k -> dst[(k*128+f)*O+o] fp16
__global__ void k_gru_repack(fp16* __restrict__ dst, const float* __restrict__ src, int O) {
  int i = blockIdx.x * 256 + threadIdx.x;
  if (i >= 512 * O) return;
  int o = i % O;
  int f = (i / O) & 127;
  int k = i / (O * 128);
  dst[i] = (fp16)src[(f * 4 + k) * O + o];
}

// ---------- laplacian (writes fp16) ----------
__global__ void k_dinv(const float* __restrict__ adj, float* __restrict__ dinv) {
  int row = blockIdx.x;
  float s = 0.f;
  for (int j = threadIdx.x; j < NN; j += 256) {
    s += fmaxf(adj[(long long)row * NN + j], adj[(long long)j * NN + row]);
  }
  __shared__ float red[256];
  red[threadIdx.x] = s;
  __syncthreads();
  for (int st = 128; st > 0; st >>= 1) {
    if (threadIdx.x < st) red[threadIdx.x] += red[threadIdx.x + st];
    __syncthreads();
  }
  if (threadIdx.x == 0) {
    float d = red[0];
    dinv[row] = d > 0.f ? 1.0f / sqrtf(d) : 0.f;
  }
}

__global__ void k_L(const float* __restrict__ adj, const float* __restrict__ dinv,
                    fp16* __restrict__ Lh) {
  long long i = (long long)blockIdx.x * 256 + threadIdx.x;
  if (i >= (long long)NN * NN) return;
  int r = (int)(i / NN), c = (int)(i % NN);
  float a = fmaxf(adj[(long long)r * NN + c], adj[(long long)c * NN + r]);
  Lh[i] = (fp16)(-dinv[r] * a * dinv[c]);
}

// ---------- gumbel softmax -> fp16 ----------
__global__ void k_gumbel_softmax(const float* __restrict__ ml, const float* __restrict__ gn,
                                 fp16* __restrict__ mZ) {
  int row = blockIdx.x;
  __shared__ float buf[CC];
  __shared__ float red[256];
  int t = threadIdx.x;
  float mx = -1e30f;
  for (int j = t; j < CC; j += 256) {
    float u = gn[(long long)row * CC + j];
    float g = -logf(-logf(u + 1e-20f) + 1e-20f);
    float v = ml[(long long)row * CC + j] + g;
    buf[j] = v;
    mx = fmaxf(mx, v);
  }
  red[t] = mx;
  __syncthreads();
  for (int st = 128; st > 0; st >>= 1) {
    if (t < st) red[t] = fmaxf(red[t], red[t + st]);
    __syncthreads();
  }
  mx = red[0];
  __syncthreads();
  float s = 0.f;
  for (int j = t; j < CC; j += 256) {
    float e = expf(buf[j] - mx);
    buf[j] = e;
    s += e;
  }
  red[t] = s;
  __syncthreads();
  for (int st = 128; st > 0; st >>= 1) {
    if (t < st) red[t] += red[t + st];
    __syncthreads();
  }
  float inv = 1.0f / red[0];
  for (int j = t; j < CC; j += 256) mZ[(long long)row * CC + j] = (fp16)(buf[j] * inv);
}

__global__ void k_te(const int* __restrict__ TE, const float* __restrict__ w1,
                     const float* __restrict__ b1, float* __restrict__ tmp) {
  int i = blockIdx.x * 256 + threadIdx.x;
  if (i >= BB * PP * 64) return;
  int j = i & 63;
  int bp = i >> 6;
  int b = bp / PP, p = bp % PP;
  int te0 = TE[(b * (PP + QQ) + p) * 2 + 0];
  int te1 = TE[(b * (PP + QQ) + p) * 2 + 1];
  float v = w1[te0 * 64 + j] + w1[(7 + te1) * 64 + j] + b1[j];
  tmp[i] = fmaxf(v, 0.f);
}

__global__ void k_zf1(const float* __restrict__ Z, const float* __restrict__ w1,
                      const float* __restrict__ b1, fp16* __restrict__ tmp) {
  long long i = (long long)blockIdx.x * 256 + threadIdx.x;
  if (i >= (long long)BB * PP * CC * 64) return;
  int j = (int)(i & 63);
  long long row = i >> 6;
  float v = Z[row * 2 + 0] * w1[j] + Z[row * 2 + 1] * w1[64 + j] + b1[j];
  tmp[i] = (fp16)fmaxf(v, 0.f);
}

__global__ void k_add_stez(fp16* __restrict__ Zf, const float* __restrict__ seZ,
                           const float* __restrict__ teZ) {
  long long i = (long long)blockIdx.x * 256 + threadIdx.x;
  if (i >= (long long)BB * PP * CC * 64) return;
  int j = (int)(i & 63);
  long long row = i >> 6;
  int c = (int)(row % CC);
  int bp = (int)(row / CC);
  Zf[i] = (fp16)((float)Zf[i] + seZ[c * 64 + j] + teZ[bp * 64 + j]);
}

// ---------- generic fp32-path GEMM (small ops) ----------
template <typename TA, typename TB, typename TC>
__global__ __launch_bounds__(256) void gemm_t(
    const TA* __restrict__ A, int lda, long long sA,
    const TB* __restrict__ Bm, int ldb, long long sB,
    TC* Cm, int ldc, long long sC,
    const TC* S, long long sS,
    const float* __restrict__ bias,
    int M, int Ncols, int K, float alpha, float beta, int act) {
  int bz = blockIdx.z;
  A += (long long)bz * sA;
  Bm += (long long)bz * sB;
  Cm += (long long)bz * sC;
  if (S) S += (long long)bz * sS;
  const int row0 = blockIdx.x * 64, col0 = blockIdx.y * 64;
  __shared__ float As[16][68];
  __shared__ float Bs[16][68];
  int tid = threadIdx.x, tx = tid & 15, ty = tid >> 4;
  float acc[4][4] = {};
  for (int k0 = 0; k0 < K; k0 += 16) {
#pragma unroll
    for (int j = 0; j < 4; ++j) {
      int e = tid + 256 * j;
      int m = e >> 4, kk = e & 15;
      int gm = row0 + m;
      As[kk][m] = (gm < M) ? ldf(A[(long long)gm * lda + k0 + kk]) : 0.f;
    }
#pragma unroll
    for (int j = 0; j < 4; ++j) {
      int e = tid + 256 * j;
      int kk = e >> 6, n = e & 63;
      int gn = col0 + n;
      Bs[kk][n] = (gn < Ncols) ? ldf(Bm[(long long)(k0 + kk) * ldb + gn]) : 0.f;
    }
    __syncthreads();
#pragma unroll
    for (int kk = 0; kk < 16; ++kk) {
      float a[4], bb[4];
#pragma unroll
      for (int i = 0; i < 4; ++i) a[i] = As[kk][ty * 4 + i];
#pragma unroll
      for (int j = 0; j < 4; ++j) bb[j] = Bs[kk][tx * 4 + j];
#pragma unroll
      for (int i = 0; i < 4; ++i)
#pragma unroll
        for (int j = 0; j < 4; ++j) acc[i][j] = fmaf(a[i], bb[j], acc[i][j]);
    }
    __syncthreads();
  }
#pragma unroll
  for (int i = 0; i < 4; ++i) {
    int r = row0 + ty * 4 + i;
    if (r >= M) continue;
#pragma unroll
    for (int j = 0; j < 4; ++j) {
      int cn = col0 + tx * 4 + j;
      if (cn >= Ncols) continue;
      float v = alpha * acc[i][j];
      if (bias) v += bias[cn];
      if (S) v += beta * ldf(S[(long long)r * ldc + cn]);
      if (act == 1) v = fmaxf(v, 0.f);
      else if (act == 2) v = 1.f / (1.f + expf(-v));
      else if (act == 3) v = tanhf(v);
      stf(&Cm[(long long)r * ldc + cn], v);
    }
  }
}

// ---------- MFMA fp16 GEMM: C = act(alpha*A@B + bias + beta*S) ----------
template <typename TC>
__global__ __launch_bounds__(256) void mfma_gemm(
    const fp16* __restrict__ A, int lda, int aShift, long long aSlab, int aHi,
    const fp16* __restrict__ B, int ldb, long long bBatch, int bShift, long long bSlab,
    TC* __restrict__ C, int ldc, long long cBatch,
    const TC* __restrict__ S, float beta,
    const float* __restrict__ bias,
    int M, int Ncols, int K, float alpha, int act) {
  __shared__ fp16 As[128][40];
  __shared__ fp16 Bs[64][40];
  const int z = blockIdx.z;
  const int gm0 = blockIdx.x * 128, n0 = blockIdx.y * 64;
  B += (long long)z * bBatch;
  C += (long long)z * cBatch;
  if (S) S += (long long)z * cBatch;
  const int tid = threadIdx.x;
  const int lane = tid & 63, wv = tid >> 6;
  const int wr = wv >> 1, wc = wv & 1;
  const int quad = lane >> 4, ln = lane & 15;
  const unsigned aMask = (1u << aShift) - 1u;
  const unsigned bMask = (1u << bShift) - 1u;
  f32x4 acc[4][2];
#pragma unroll
  for (int i = 0; i < 4; ++i)
#pragma unroll
    for (int j = 0; j < 2; ++j) acc[i][j] = (f32x4){0.f, 0.f, 0.f, 0.f};

  for (int k0 = 0; k0 < K; k0 += 32) {
#pragma unroll
    for (int i = 0; i < 2; ++i) {
      int c = tid + 256 * i;
      int row = c >> 2, seg = c & 3;
      int gm = gm0 + row;
      int kk0 = k0 + seg * 8;
      int slab = (int)((unsigned)kk0 >> aShift);
      int kin = (int)((unsigned)kk0 & aMask);
      int ceff = kin + (kin >= 64 ? aHi : 0);
      const fp16* src = A + (long long)slab * aSlab + (long long)gm * lda + ceff;
      if (gm < M && kk0 + 8 <= K) {
        *(f16x8*)&As[row][seg * 8] = *(const f16x8*)src;
      } else {
#pragma unroll
        for (int j = 0; j < 8; ++j)
          As[row][seg * 8 + j] = (gm < M && kk0 + j < K) ? src[j] : (fp16)0.f;
      }
    }
    {
      int kk = k0 + (tid & 31);
      int ngrp = tid >> 5;
      int slab = (int)((unsigned)kk >> bShift);
      int kin = (int)((unsigned)kk & bMask);
      int n = n0 + ngrp * 8;
      const fp16* src = B + (long long)slab * bSlab + (long long)kin * ldb + n;
      if (kk < K && n + 8 <= Ncols) {
        f16x8 v = *(const f16x8*)src;
#pragma unroll
        for (int j = 0; j < 8; ++j) Bs[ngrp * 8 + j][tid & 31] = v[j];
      } else {
#pragma unroll
        for (int j = 0; j < 8; ++j)
          Bs[ngrp * 8 + j][tid & 31] = (kk < K && n + j < Ncols) ? src[j] : (fp16)0.f;
      }
    }
    __syncthreads();
    f16x8 af[4], bf[2];
#pragma unroll
    for (int wm = 0; wm < 4; ++wm)
      af[wm] = *(const f16x8*)&As[wr * 64 + wm * 16 + ln][quad * 8];
#pragma unroll
    for (int wn = 0; wn < 2; ++wn)
      bf[wn] = *(const f16x8*)&Bs[wc * 32 + wn * 16 + ln][quad * 8];
#pragma unroll
    for (int wm = 0; wm < 4; ++wm)
#pragma unroll
      for (int wn = 0; wn < 2; ++wn)
        acc[wm][wn] =
            __builtin_amdgcn_mfma_f32_16x16x32_f16(af[wm], bf[wn], acc[wm][wn], 0, 0, 0);
    __syncthreads();
  }
#pragma unroll
  for (int wm = 0; wm < 4; ++wm) {
#pragma unroll
    for (int wn = 0; wn < 2; ++wn) {
#pragma unroll
      for (int r = 0; r < 4; ++r) {
        int gm = gm0 + wr * 64 + wm * 16 + quad * 4 + r;
        int gn = n0 + wc * 32 + wn * 16 + ln;
        if (gm < M && gn < Ncols) {
          float v = alpha * acc[wm][wn][r];
          if (bias) v += bias[gn];
          if (S) v += beta * ldf(S[(long long)gm * ldc + gn]);
          if (act == 1) v = fmaxf(v, 0.f);
          else if (act == 2) v = 1.f / (1.f + expf(-v));
          else if (act == 3) v = tanhf(v);
          stf(&C[(long long)gm * ldc + gn], v);
        }
      }
    }
  }
}

// ---------- ConvLSTM conv as MFMA: gates = conv(x,wx)+conv(h,wh) ----------
// M = B*1024 rows (b,y,x), N = 256 couts, K = 1152 = 2 src * 9 taps * 64 ci.
// wcat: (1152,256) fp16 = [wx(576,256); wh(576,256)] (native (3,3,64,co) flattening).
__global__ __launch_bounds__(256) void k_conv_mfma(
    const fp16* __restrict__ Zf, const fp16* __restrict__ h,
    const fp16* __restrict__ wcat, fp16* __restrict__ gates, int p) {
  __shared__ fp16 As[128][40];
  __shared__ fp16 Bs[64][40];
  const int gm0 = blockIdx.x * 128, n0 = blockIdx.y * 64;
  const int tid = threadIdx.x;
  const int lane = tid & 63, wv = tid >> 6;
  const int wr = wv >> 1, wc = wv & 1;
  const int quad = lane >> 4, ln = lane & 15;
  f32x4 acc[4][2];
#pragma unroll
  for (int i = 0; i < 4; ++i)
#pragma unroll
    for (int j = 0; j < 2; ++j) acc[i][j] = (f32x4){0.f, 0.f, 0.f, 0.f};

  for (int kb = 0; kb < 36; ++kb) {
    const int srcsel = kb >= 18;
    const int tap = (kb >> 1) % 9;
    const int half = kb & 1;
    const int dy = tap / 3 - 1, dx = tap % 3 - 1;
    // A-stage: shifted window with zero-fill at image boundary
#pragma unroll
    for (int i = 0; i < 2; ++i) {
      int c = tid + 256 * i;
      int row = c >> 2, seg = c & 3;
      int m = gm0 + row;
      int b = m >> 10;
      int y = (m >> 5) & 31, x = m & 31;
      int yy = y + dy, xx = x + dx;
      bool valid = ((unsigned)yy < 32u) && ((unsigned)xx < 32u);
      f16x8 v;
      if (valid) {
        long long cell = ((long long)b << 10) + (yy << 5) + xx;
        const fp16* sp =
            srcsel ? (h + cell * 64)
                   : (Zf + ((((long long)(b * PP + p)) << 10) + (yy << 5) + xx) * 64);
        v = *(const f16x8*)(sp + half * 32 + seg * 8);
      } else {
#pragma unroll
        for (int j = 0; j < 8; ++j) v[j] = (fp16)0.f;
      }
      *(f16x8*)&As[row][seg * 8] = v;
    }
    // B-stage: wcat row kk, transposed into Bs[n][k]
    {
      int kk = kb * 32 + (tid & 31);
      int ngrp = tid >> 5;
      int n = n0 + ngrp * 8;
      f16x8 v = *(const f16x8*)(wcat + (long long)kk * 256 + n);
#pragma unroll
      for (int j = 0; j < 8; ++j) Bs[ngrp * 8 + j][tid & 31] = v[j];
    }
    __syncthreads();
    f16x8 af[4], bf[2];
#pragma unroll
    for (int wm = 0; wm < 4; ++wm)
      af[wm] = *(const f16x8*)&As[wr * 64 + wm * 16 + ln][quad * 8];
#pragma unroll
    for (int wn = 0; wn < 2; ++wn)
      bf[wn] = *(const f16x8*)&Bs[wc * 32 + wn * 16 + ln][quad * 8];
#pragma unroll
    for (int wm = 0; wm < 4; ++wm)
#pragma unroll
      for (int wn = 0; wn < 2; ++wn)
        acc[wm][wn] =
            __builtin_amdgcn_mfma_f32_16x16x32_f16(af[wm], bf[wn], acc[wm][wn], 0, 0, 0);
    __syncthreads();
  }
#pragma unroll
  for (int wm = 0; wm < 4; ++wm)
#pragma unroll
    for (int wn = 0; wn < 2; ++wn)
#pragma unroll
      for (int r = 0; r < 4; ++r) {
        int gm = gm0 + wr * 64 + wm * 16 + quad * 4 + r;
        int gn = n0 + wc * 32 + wn * 16 + ln;
        gates[(long long)gm * 256 + gn] = (fp16)acc[wm][wn][r];
      }
}

__global__ void k_clstm_update(const fp16* __restrict__ gates, float* __restrict__ c,
                               fp16* __restrict__ h, fp16* __restrict__ Zc, int p) {
  long long i = (long long)blockIdx.x * 256 + threadIdx.x;
  if (i >= (long long)BB * CC * 64) return;
  int d = (int)(i & 63);
  long long bc = i >> 6;
  int b = (int)(bc >> 10);
  int cell = (int)(bc & 1023);
  const fp16* g = gates + (((long long)b * CC) + cell) * 256;
  float gi = (float)g[d], gf = (float)g[64 + d], gg = (float)g[128 + d],
        go = (float)g[192 + d];
  float hs_f = fminf(fmaxf(0.2f * gf + 0.5f, 0.f), 1.f);
  float hs_i = fminf(fmaxf(0.2f * gi + 0.5f, 0.f), 1.f);
  float hs_o = fminf(fmaxf(0.2f * go + 0.5f, 0.f), 1.f);
  float cv = hs_f * c[i] + hs_i * tanhf(gg);
  c[i] = cv;
  float hv = hs_o * tanhf(cv);
  h[i] = (fp16)hv;
  Zc[(((long long)(b * PP + p)) * CC + cell) * 64 + d] = (fp16)hv;
}

// ---------- Xf = mlp2(X) + STEX + ZX (in place into ZX fp16) ----------
__global__ __launch_bounds__(256) void k_xf_build(
    const float* __restrict__ X, const float* __restrict__ w1, const float* __restrict__ b1,
    const float* __restrict__ w2, const float* __restrict__ b2v,
    const float* __restrict__ seX, const float* __restrict__ teX, fp16* Xf) {
  __shared__ float w2s[64][65];
  __shared__ float ts[4][64];
  int tid = threadIdx.x;
  for (int e = tid; e < 4096; e += 256) w2s[e >> 6][e & 63] = w2[e];
  long long row0 = (long long)blockIdx.x * 4;
  int r = tid >> 6, j = tid & 63;
  long long row = row0 + r;
  float t = 0.f;
  bool ok = row < (long long)BB * PP * NN;
  if (ok) t = fmaxf(X[row] * w1[j] + b1[j], 0.f);
  ts[r][j] = t;
  __syncthreads();
  if (ok) {
    float acc = 0.f;
#pragma unroll
    for (int kk = 0; kk < 64; ++kk) acc = fmaf(ts[r][kk], w2s[kk][j], acc);
    int n = (int)(row % NN);
    int bp = (int)(row / NN);
    long long o = row * 64 + j;
    Xf[o] = (fp16)((float)Xf[o] + acc + b2v[j] + seX[n * 64 + j] + teX[bp * 64 + j]);
  }
}

// ---------- DCGRU builders ----------
__global__ void k_u0_gate(const fp16* __restrict__ ZX, const float* __restrict__ hg,
                          fp16* __restrict__ U0, int p) {
  long long i = (long long)blockIdx.x * 256 + threadIdx.x;
  if (i >= (long long)BB * NN * 128) return;
  int d = (int)(i & 127);
  long long row = i >> 7;
  int b = (int)(row / NN);
  int n = (int)(row % NN);
  float v = (d < 64) ? (float)ZX[(((long long)(b * PP + p)) * NN + n) * 64 + d]
                     : hg[row * 64 + (d - 64)];
  U0[row * 192 + d] = (fp16)v;
}

__global__ void k_u0_cand(const float* __restrict__ ru, const float* __restrict__ hg,
                          fp16* __restrict__ U0) {
  long long i = (long long)blockIdx.x * 256 + threadIdx.x;
  if (i >= (long long)BB * NN * 64) return;
  int d = (int)(i & 63);
  long long row = i >> 6;
  U0[row * 192 + 128 + d] = (fp16)(ru[row * 128 + d] * hg[row * 64 + d]);
}

__global__ void k_h_update(float* __restrict__ h, const float* __restrict__ ru,
                           const float* __restrict__ cnd) {
  long long i = (long long)blockIdx.x * 256 + threadIdx.x;
  if (i >= (long long)BB * NN * 64) return;
  int d = (int)(i & 63);
  long long bn = i >> 6;
  float u = ru[bn * 128 + 64 + d];
  h[i] = u * h[i] + (1.f - u) * cnd[i];
}

__global__ void k_out(const float* __restrict__ Y, float* __restrict__ out) {
  int i = blockIdx.x * 256 + threadIdx.x;
  if (i >= BB * QQ * NN) return;
  int n = i % NN;
  int bq = i / NN;
  int b = bq / QQ, q = bq % QQ;
  out[i] = Y[((long long)b * NN + n) * 12 + q];
}

// ---------- host helpers ----------
template <typename TA, typename TB, typename TC>
static void launch_gemm(hipStream_t stream, const TA* A, int lda, long long sA,
                        const TB* Bm, int ldb, long long sB, TC* Cm, int ldc, long long sC,
                        const TC* S, long long sS, const float* bias, int M, int Nc, int K,
                        float alpha, float beta, int act, int batch) {
  dim3 g((M + 63) / 64, (Nc + 63) / 64, batch);
  gemm_t<TA, TB, TC><<<g, dim3(256), 0, stream>>>(A, lda, sA, Bm, ldb, sB, Cm, ldc, sC, S,
                                                  sS, bias, M, Nc, K, alpha, beta, act);
}

template <typename TC>
static void launch_mfma(hipStream_t stream, const fp16* A, int lda, int aShift,
                        long long aSlab, int aHi, const fp16* B, int ldb, long long bBatch,
                        int bShift, long long bSlab, TC* C, int ldc, long long cBatch,
                        const TC* S, float beta, const float* bias, int M, int Nc, int K,
                        float alpha, int act, int batch) {
  dim3 g((M + 127) / 128, (Nc + 63) / 64, batch);
  mfma_gemm<TC><<<g, dim3(256), 0, stream>>>(A, lda, aShift, aSlab, aHi, B, ldb, bBatch,
                                             bShift, bSlab, C, ldc, cBatch, S, beta, bias,
                                             M, Nc, K, alpha, act);
}

extern "C" void kernel_launch(void* const* d_in, const int* in_sizes, int n_in,
                              void* d_out, int out_size, void* d_ws, size_t ws_size,
                              hipStream_t stream) {
  char* base = (char*)d_ws;
  size_t off = 0;
  auto alloc_bytes = [&](size_t nb) -> char* {
    char* p = base + off;
    off += (nb + 255) & ~(size_t)255;
    return p;
  };
  auto allocf = [&](size_t n) -> float* { return (float*)alloc_bytes(n * 4); };
  auto alloch = [&](size_t n) -> fp16* { return (fp16*)alloc_bytes(n * 2); };

  const float* X = (const float*)d_in[0];
  const float* Z = (const float*)d_in[1];
  const int* TE = (const int*)d_in[2];
  const float* adj_gg = (const float*)d_in[3];
  const float* adj_gr = (const float*)d_in[4];
  const float* gumbel = (const float*)d_in[5];
  const float* se_x = (const float*)d_in[6];
  const float* se_z = (const float*)d_in[7];
  const float* movement = (const float*)d_in[8];
  auto W = [&](int i) { return (const float*)d_in[i]; };

  // ---- allocations ----
  fp16* wcat = alloch(1152 * 256);  // [wx(576,256); wh(576,256)]
  fp16* gwh = alloch(65536);
  fp16* cwh = alloch(32768);
  float* dinv = allocf(NN);
  fp16* Lh = alloch((size_t)NN * NN);
  fp16* mZh = alloch((size_t)CC * CC);
  fp16* agh = alloch((size_t)NN * CC);
  float* seZ = allocf(CC * 64);
  float* teZ = allocf(BB * PP * 64);
  float* seX = allocf(NN * 64);
  float* teX = allocf(BB * PP * 64);
  float* mtmp = allocf(NN * 64);
  float* tetmp = allocf(BB * PP * 64);
  float* hg = allocf((size_t)BB * NN * 64);
  float* ru = allocf((size_t)BB * NN * 128);
  float* cnd = allocf((size_t)BB * NN * 64);
  // U slabs: 4 x [16][2000][192] fp16; ConvLSTM {gates, chh(fp16), ccc(fp32)} aliased inside
  const long long SLAB = (long long)BB * NN * 192;
  fp16* Uall = alloch((size_t)4 * SLAB);
  fp16* gates = (fp16*)Uall;                          // 16*1024*256 fp16 = 8.39 MB
  fp16* chh = (fp16*)((char*)Uall + 8388608);         // 16*1024*64 fp16 = 2.10 MB
  float* ccc = (float*)((char*)Uall + 12582912);      // 16*1024*64 f32  = 4.19 MB
  // zpool: Zf (B,P,C,64) aliased by ZX (B,P,N,64); Zc separate
  fp16* zpool = alloch((size_t)BB * PP * NN * 64);
  fp16* Zf = zpool;
  fp16* ZX = zpool;
  fp16* Zc = alloch((size_t)BB * PP * CC * 64);

  if (off > ws_size) return;  // soft-fail diagnostic

  // ---- precompute ----
  k_f2h<<<dim3((576 * 256 + 255) / 256), dim3(256), 0, stream>>>(wcat, W(39), 576 * 256);
  k_f2h<<<dim3((576 * 256 + 255) / 256), dim3(256), 0, stream>>>(wcat + 576 * 256, W(40),
                                                                 576 * 256);
  k_gru_repack<<<dim3(256), dim3(256), 0, stream>>>(gwh, W(41), 128);
  k_gru_repack<<<dim3(128), dim3(256), 0, stream>>>(cwh, W(43), 64);
  k_dinv<<<dim3(NN), dim3(256), 0, stream>>>(adj_gg, dinv);
  k_L<<<dim3((NN * NN + 255) / 256), dim3(256), 0, stream>>>(adj_gg, dinv, Lh);
  k_gumbel_softmax<<<dim3(CC), dim3(256), 0, stream>>>(movement, gumbel, mZh);
  k_f2h<<<dim3((NN * CC + 255) / 256), dim3(256), 0, stream>>>(agh, adj_gr,
                                                               (long long)NN * CC);

  // ---- STEZ ----
  launch_gemm(stream, se_z, 64, 0LL, W(17), 64, 0LL, mtmp, 64, 0LL, (float*)nullptr, 0LL,
              W(18), CC, 64, 64, 1.f, 0.f, 1, 1);
  launch_gemm(stream, (const float*)mtmp, 64, 0LL, W(19), 64, 0LL, seZ, 64, 0LL,
              (float*)nullptr, 0LL, W(20), CC, 64, 64, 1.f, 0.f, 0, 1);
  k_te<<<dim3((BB * PP * 64 + 255) / 256), dim3(256), 0, stream>>>(TE, W(21), W(22), tetmp);
  launch_gemm(stream, (const float*)tetmp, 64, 0LL, W(23), 64, 0LL, teZ, 64, 0LL,
              (float*)nullptr, 0LL, W(24), BB * PP, 64, 64, 1.f, 0.f, 0, 1);

  // ---- Zf = mlp2(Z) + STEZ (Zc as layer-1 scratch) ----
  long long nZ = (long long)BB * PP * CC * 64;
  k_zf1<<<dim3((int)((nZ + 255) / 256)), dim3(256), 0, stream>>>(Z, W(25), W(26), Zc);
  launch_gemm(stream, (const fp16*)Zc, 64, 0LL, W(27), 64, 0LL, Zf, 64, 0LL,
              (fp16*)nullptr, 0LL, W(28), BB * PP * CC, 64, 64, 1.f, 0.f, 0, 1);
  k_add_stez<<<dim3((int)((nZ + 255) / 256)), dim3(256), 0, stream>>>(Zf, seZ, teZ);

  // ---- ConvLSTM (MFMA conv) ----
  hipMemsetAsync(chh, 0, (size_t)BB * CC * 64 * 2, stream);
  hipMemsetAsync(ccc, 0, (size_t)BB * CC * 64 * 4, stream);
  for (int p = 0; p < PP; ++p) {
    k_conv_mfma<<<dim3(BB * CC / 128, 4), dim3(256), 0, stream>>>(Zf, chh, wcat, gates, p);
    k_clstm_update<<<dim3((int)(((long long)BB * CC * 64 + 255) / 256)), dim3(256), 0,
                     stream>>>(gates, ccc, chh, Zc, p);
  }

  // ---- movement chain: Zf <- mZ@Zc ; Zc <- relu(Zf@W+b) ; ZX <- adj_gr@Zc ----
  launch_mfma<fp16>(stream, mZh, CC, 31, 0LL, 0, (const fp16*)Zc, 64, (long long)CC * 64,
                    31, 0LL, Zf, 64, (long long)CC * 64, (const fp16*)nullptr, 0.f, nullptr,
                    CC, 64, CC, 1.f, 0, BB * PP);
  launch_gemm(stream, (const fp16*)Zf, 64, 0LL, W(33), 64, 0LL, Zc, 64, 0LL,
              (fp16*)nullptr, 0LL, W(34), BB * PP * CC, 64, 64, 1.f, 0.f, 1, 1);
  launch_mfma<fp16>(stream, agh, CC, 31, 0LL, 0, (const fp16*)Zc, 64, (long long)CC * 64,
                    31, 0LL, ZX, 64, (long long)NN * 64, (const fp16*)nullptr, 0.f, nullptr,
                    NN, 64, CC, 1.f, 0, BB * PP);

  // ---- STEX ----
  launch_gemm(stream, se_x, 64, 0LL, W(9), 64, 0LL, mtmp, 64, 0LL, (float*)nullptr, 0LL,
              W(10), NN, 64, 64, 1.f, 0.f, 1, 1);
  launch_gemm(stream, (const float*)mtmp, 64, 0LL, W(11), 64, 0LL, seX, 64, 0LL,
              (float*)nullptr, 0LL, W(12), NN, 64, 64, 1.f, 0.f, 0, 1);
  k_te<<<dim3((BB * PP * 64 + 255) / 256), dim3(256), 0, stream>>>(TE, W(13), W(14), tetmp);
  launch_gemm(stream, (const float*)tetmp, 64, 0LL, W(15), 64, 0LL, teX, 64, 0LL,
              (float*)nullptr, 0LL, W(16), BB * PP, 64, 64, 1.f, 0.f, 0, 1);

  // ---- Xf (in place into ZX) ----
  k_xf_build<<<dim3(BB * PP * NN / 4), dim3(256), 0, stream>>>(X, W(29), W(30), W(31),
                                                               W(32), seX, teX, ZX);

  // ---- DCGRU ----
  hipMemsetAsync(hg, 0, (size_t)BB * NN * 64 * 4, stream);
  const long long bStr = (long long)NN * 192;
  fp16* U0 = Uall;
  fp16* U1 = Uall + SLAB;
  fp16* U2 = Uall + 2 * SLAB;
  fp16* U3 = Uall + 3 * SLAB;
  const long long n128 = (long long)BB * NN * 128;
  const long long n64 = (long long)BB * NN * 64;
  for (int p = 0; p < PP; ++p) {
    k_u0_gate<<<dim3((int)((n128 + 255) / 256)), dim3(256), 0, stream>>>(ZX, hg, U0, p);
    launch_mfma<fp16>(stream, Lh, NN, 31, 0LL, 0, U0, 192, bStr, 31, 0LL, U1, 192, bStr,
                      (const fp16*)nullptr, 0.f, nullptr, NN, 128, NN, 1.f, 0, BB);
    launch_mfma<fp16>(stream, Lh, NN, 31, 0LL, 0, U1, 192, bStr, 31, 0LL, U2, 192, bStr,
                      (const fp16*)U0, -1.f, nullptr, NN, 128, NN, 2.f, 0, BB);
    launch_mfma<fp16>(stream, Lh, NN, 31, 0LL, 0, U2, 192, bStr, 31, 0LL, U3, 192, bStr,
                      (const fp16*)U1, -1.f, nullptr, NN, 128, NN, 2.f, 0, BB);
    launch_mfma<float>(stream, Uall, 192, 7, SLAB, 0, gwh, 128, 0LL, 7, 16384LL, ru, 128,
                       0LL, (const float*)nullptr, 0.f, W(42), BB * NN, 128, 512, 1.f, 2, 1);
    k_u0_cand<<<dim3((int)((n64 + 255) / 256)), dim3(256), 0, stream>>>(ru, hg, U0);
    launch_mfma<fp16>(stream, Lh, NN, 31, 0LL, 0, U0 + 128, 192, bStr, 31, 0LL, U1 + 128,
                      192, bStr, (const fp16*)nullptr, 0.f, nullptr, NN, 64, NN, 1.f, 0, BB);
    launch_mfma<fp16>(stream, Lh, NN, 31, 0LL, 0, U1 + 128, 192, bStr, 31, 0LL, U2 + 128,
                      192, bStr, (const fp16*)(U0 + 128), -1.f, nullptr, NN, 64, NN, 2.f, 0,
                      BB);
    launch_mfma<fp16>(stream, Lh, NN, 31, 0LL, 0, U2 + 128, 192, bStr, 31, 0LL, U3 + 128,
                      192, bStr, (const fp16*)(U1 + 128), -1.f, nullptr, NN, 64, NN, 2.f, 0,
                      BB);
    launch_mfma<float>(stream, Uall, 192, 7, SLAB, 64, cwh, 64, 0LL, 7, 8192LL, cnd, 64,
                       0LL, (const float*)nullptr, 0.f, W(44), BB * NN, 64, 512, 1.f, 3, 1);
    k_h_update<<<dim3((int)((n64 + 255) / 256)), dim3(256), 0, stream>>>(hg, ru, cnd);
  }

  // ---- output head ----
  launch_gemm(stream, (const float*)hg, 64, 0LL, W(35), 64, 0LL, ru, 64, 0LL,
              (float*)nullptr, 0LL, W(36), BB * NN, 64, 64, 1.f, 0.f, 1, 1);
  launch_gemm(stream, (const float*)ru, 64, 0LL, W(37), 12, 0LL, cnd, 12, 0LL,
              (float*)nullptr, 0LL, W(38), BB * NN, 12, 64, 1.f, 0.f, 0, 1);
  k_out<<<dim3((BB * QQ * NN + 255) / 256), dim3(256), 0, stream>>>(cnd, (float*)d_out);
}

// Round 6
// 7398.396 us; speedup vs baseline: 3.6133x; 1.1704x over previous
//
#include <hip/hip_runtime.h>
#include <hip/hip_bf16.h>
#include <math.h>

typedef _Float16 fp16;
typedef _Float16 f16x8 __attribute__((ext_vector_type(8)));
typedef float f32x4 __attribute__((ext_vector_type(4)));

#define BB 16
#define PP 12
#define QQ 12
#define NN 2000
#define CC 1024

static __device__ __forceinline__ float ldf(float v) { return v; }
static __device__ __forceinline__ float ldf(fp16 v) { return (float)v; }
static __device__ __forceinline__ void stf(float* p, float v) { *p = v; }
static __device__ __forceinline__ void stf(fp16* p, float v) { *p = (fp16)v; }

// ---------- conversions / repacks ----------
__global__ void k_f2h(fp16* __restrict__ dst, const float* __restrict__ src, long long n) {
  long long i = (long long)blockIdx.x * 256 + threadIdx.x;
  if (i < n) dst[i] = (fp16)src[i];
}

// dcgru weights (512,O): row=f*4+t -> Wt[d][t*128+c] = src[(c*4+t)*O+d]
__global__ void k_gru_repackT(fp16* __restrict__ dst, const float* __restrict__ src, int O) {
  int i = blockIdx.x * 256 + threadIdx.x;
  if (i >= O * 512) return;
  int d = i >> 9;
  int kc = i & 511;
  int t = kc >> 7;
  int c = kc & 127;
  dst[i] = (fp16)src[(c * 4 + t) * O + d];
}

// w2 (64,64) -> w2T[d][k] fp16
__global__ void k_w2T(fp16* __restrict__ dst, const float* __restrict__ src) {
  int i = blockIdx.x * 256 + threadIdx.x;
  if (i >= 4096) return;
  int d = i >> 6, k = i & 63;
  dst[i] = (fp16)src[k * 64 + d];
}

// ---------- laplacian (fp16, symmetric) ----------
__global__ void k_dinv(const float* __restrict__ adj, float* __restrict__ dinv) {
  int row = blockIdx.x;
  float s = 0.f;
  for (int j = threadIdx.x; j < NN; j += 256)
    s += fmaxf(adj[(long long)row * NN + j], adj[(long long)j * NN + row]);
  __shared__ float red[256];
  red[threadIdx.x] = s;
  __syncthreads();
  for (int st = 128; st > 0; st >>= 1) {
    if (threadIdx.x < st) red[threadIdx.x] += red[threadIdx.x + st];
    __syncthreads();
  }
  if (threadIdx.x == 0) {
    float d = red[0];
    dinv[row] = d > 0.f ? 1.0f / sqrtf(d) : 0.f;
  }
}

__global__ void k_L(const float* __restrict__ adj, const float* __restrict__ dinv,
                    fp16* __restrict__ Lh) {
  long long i = (long long)blockIdx.x * 256 + threadIdx.x;
  if (i >= (long long)NN * NN) return;
  int r = (int)(i / NN), c = (int)(i % NN);
  float a = fmaxf(adj[(long long)r * NN + c], adj[(long long)c * NN + r]);
  Lh[i] = (fp16)(-dinv[r] * a * dinv[c]);
}

// ---------- gumbel softmax -> fp16 ----------
__global__ void k_gumbel_softmax(const float* __restrict__ ml, const float* __restrict__ gn,
                                 fp16* __restrict__ mZ) {
  int row = blockIdx.x;
  __shared__ float buf[CC];
  __shared__ float red[256];
  int t = threadIdx.x;
  float mx = -1e30f;
  for (int j = t; j < CC; j += 256) {
    float u = gn[(long long)row * CC + j];
    float g = -logf(-logf(u + 1e-20f) + 1e-20f);
    float v = ml[(long long)row * CC + j] + g;
    buf[j] = v;
    mx = fmaxf(mx, v);
  }
  red[t] = mx;
  __syncthreads();
  for (int st = 128; st > 0; st >>= 1) {
    if (t < st) red[t] = fmaxf(red[t], red[t + st]);
    __syncthreads();
  }
  mx = red[0];
  __syncthreads();
  float s = 0.f;
  for (int j = t; j < CC; j += 256) {
    float e = expf(buf[j] - mx);
    buf[j] = e;
    s += e;
  }
  red[t] = s;
  __syncthreads();
  for (int st = 128; st > 0; st >>= 1) {
    if (t < st) red[t] += red[t + st];
    __syncthreads();
  }
  float inv = 1.0f / red[0];
  for (int j = t; j < CC; j += 256) mZ[(long long)row * CC + j] = (fp16)(buf[j] * inv);
}

__global__ void k_te(const int* __restrict__ TE, const float* __restrict__ w1,
                     const float* __restrict__ b1, float* __restrict__ tmp) {
  int i = blockIdx.x * 256 + threadIdx.x;
  if (i >= BB * PP * 64) return;
  int j = i & 63;
  int bp = i >> 6;
  int b = bp / PP, p = bp % PP;
  int te0 = TE[(b * (PP + QQ) + p) * 2 + 0];
  int te1 = TE[(b * (PP + QQ) + p) * 2 + 1];
  float v = w1[te0 * 64 + j] + w1[(7 + te1) * 64 + j] + b1[j];
  tmp[i] = fmaxf(v, 0.f);
}

__global__ void k_addb(float* __restrict__ dst, const float* __restrict__ b, int n) {
  int i = blockIdx.x * 256 + threadIdx.x;
  if (i < n) dst[i] += b[i & 63];
}

__global__ void k_zf1(const float* __restrict__ Z, const float* __restrict__ w1,
                      const float* __restrict__ b1, fp16* __restrict__ tmp) {
  long long i = (long long)blockIdx.x * 256 + threadIdx.x;
  if (i >= (long long)BB * PP * CC * 64) return;
  int j = (int)(i & 63);
  long long row = i >> 6;
  float v = Z[row * 2 + 0] * w1[j] + Z[row * 2 + 1] * w1[64 + j] + b1[j];
  tmp[i] = (fp16)fmaxf(v, 0.f);
}

__global__ void k_add_stez(fp16* __restrict__ Zf, const float* __restrict__ seZ,
                           const float* __restrict__ teZ) {
  long long i = (long long)blockIdx.x * 256 + threadIdx.x;
  if (i >= (long long)BB * PP * CC * 64) return;
  int j = (int)(i & 63);
  long long row = i >> 6;
  int c = (int)(row % CC);
  int bp = (int)(row / CC);
  Zf[i] = (fp16)((float)Zf[i] + seZ[c * 64 + j] + teZ[bp * 64 + j]);
}

// ---------- generic fp32-path GEMM (small ops) ----------
template <typename TA, typename TB, typename TC>
__global__ __launch_bounds__(256) void gemm_t(
    const TA* __restrict__ A, int lda, long long sA,
    const TB* __restrict__ Bm, int ldb, long long sB,
    TC* Cm, int ldc, long long sC,
    const TC* S, long long sS,
    const float* __restrict__ bias,
    int M, int Ncols, int K, float alpha, float beta, int act) {
  int bz = blockIdx.z;
  A += (long long)bz * sA;
  Bm += (long long)bz * sB;
  Cm += (long long)bz * sC;
  if (S) S += (long long)bz * sS;
  const int row0 = blockIdx.x * 64, col0 = blockIdx.y * 64;
  __shared__ float As[16][68];
  __shared__ float Bs[16][68];
  int tid = threadIdx.x, tx = tid & 15, ty = tid >> 4;
  float acc[4][4] = {};
  for (int k0 = 0; k0 < K; k0 += 16) {
#pragma unroll
    for (int j = 0; j < 4; ++j) {
      int e = tid + 256 * j;
      int m = e >> 4, kk = e & 15;
      int gm = row0 + m;
      As[kk][m] = (gm < M) ? ldf(A[(long long)gm * lda + k0 + kk]) : 0.f;
    }
#pragma unroll
    for (int j = 0; j < 4; ++j) {
      int e = tid + 256 * j;
      int kk = e >> 6, n = e & 63;
      int gn = col0 + n;
      Bs[kk][n] = (gn < Ncols) ? ldf(Bm[(long long)(k0 + kk) * ldb + gn]) : 0.f;
    }
    __syncthreads();
#pragma unroll
    for (int kk = 0; kk < 16; ++kk) {
      float a[4], bb[4];
#pragma unroll
      for (int i = 0; i < 4; ++i) a[i] = As[kk][ty * 4 + i];
#pragma unroll
      for (int j = 0; j < 4; ++j) bb[j] = Bs[kk][tx * 4 + j];
#pragma unroll
      for (int i = 0; i < 4; ++i)
#pragma unroll
        for (int j = 0; j < 4; ++j) acc[i][j] = fmaf(a[i], bb[j], acc[i][j]);
    }
    __syncthreads();
  }
#pragma unroll
  for (int i = 0; i < 4; ++i) {
    int r = row0 + ty * 4 + i;
    if (r >= M) continue;
#pragma unroll
    for (int j = 0; j < 4; ++j) {
      int cn = col0 + tx * 4 + j;
      if (cn >= Ncols) continue;
      float v = alpha * acc[i][j];
      if (bias) v += bias[cn];
      if (S) v += beta * ldf(S[(long long)r * ldc + cn]);
      if (act == 1) v = fmaxf(v, 0.f);
      else if (act == 2) v = 1.f / (1.f + expf(-v));
      else if (act == 3) v = tanhf(v);
      stf(&Cm[(long long)r * ldc + cn], v);
    }
  }
}

// ---------- unified MFMA GEMM ----------
// C[z] = act(alpha * A[z] @ B[z] + bias + S2 + beta*S[z])
// A: row-major [m][k], k-contiguous (b128 staging).
// B: if BROW: row-major [n][k] (b128 staging). else: [k][n] with slab/cmap
//    (scalar-transpose staging): addr = B + z*bBatch + (k>>bShift)*bSlab
//    + (cmap(k&mask))*ldb + n, cmap(c) = c + (c>=64 ? bHi : 0).
// C: [m][n] (or [n][m] if TRANSC, with ldc = m-stride).
template <typename TC, int MT, bool BROW, bool TRANSC, bool BIASROW>
__global__ __launch_bounds__(256) void mfma2(
    const fp16* __restrict__ A, int lda, long long aBatch,
    const fp16* __restrict__ B, int ldb, long long bBatch, int bShift, long long bSlab,
    int bHi,
    TC* __restrict__ C, int ldc, long long cBatch,
    const TC* __restrict__ S, float beta,
    const float* __restrict__ bias, int biasBatch,
    const float* __restrict__ S2,
    int M, int Ncols, int K, float alpha, int act) {
  __shared__ fp16 As[MT][40];
  __shared__ fp16 Bs[64][40];
  const int z = blockIdx.z;
  const int gm0 = blockIdx.x * MT, n0 = blockIdx.y * 64;
  A += (long long)z * aBatch;
  B += (long long)z * bBatch;
  C += (long long)z * cBatch;
  if (S) S += (long long)z * cBatch;
  const int tid = threadIdx.x;
  const int lane = tid & 63, wv = tid >> 6;
  const int wr = wv >> 1, wc = wv & 1;
  const int quad = lane >> 4, ln = lane & 15;
  const unsigned bMask = (1u << bShift) - 1u;
  constexpr int WM = MT / 32;
  f32x4 acc[WM][2];
#pragma unroll
  for (int i = 0; i < WM; ++i)
#pragma unroll
    for (int j = 0; j < 2; ++j) acc[i][j] = (f32x4){0.f, 0.f, 0.f, 0.f};

  for (int k0 = 0; k0 < K; k0 += 32) {
    // A-stage: MT rows x 32 k, b128
#pragma unroll
    for (int i = 0; i < MT / 64; ++i) {
      int c = tid + 256 * i;
      int row = c >> 2, seg = c & 3;
      int gm = gm0 + row;
      int kk0 = k0 + seg * 8;
      const fp16* src = A + (long long)gm * lda + kk0;
      if (gm < M && kk0 + 8 <= K) {
        *(f16x8*)&As[row][seg * 8] = *(const f16x8*)src;
      } else {
#pragma unroll
        for (int j = 0; j < 8; ++j)
          As[row][seg * 8 + j] = (gm < M && kk0 + j < K) ? src[j] : (fp16)0.f;
      }
    }
    // B-stage
    if (BROW) {
      int n = tid >> 2, seg = tid & 3;
      int gn = n0 + n;
      int kk0 = k0 + seg * 8;
      const fp16* src = B + (long long)gn * ldb + kk0;
      if (gn < Ncols && kk0 + 8 <= K) {
        *(f16x8*)&Bs[n][seg * 8] = *(const f16x8*)src;
      } else {
#pragma unroll
        for (int j = 0; j < 8; ++j)
          Bs[n][seg * 8 + j] = (gn < Ncols && kk0 + j < K) ? src[j] : (fp16)0.f;
      }
    } else {
      int kk = k0 + (tid & 31);
      int ngrp = tid >> 5;
      int slab = (int)((unsigned)kk >> bShift);
      int kin = (int)((unsigned)kk & bMask);
      int col = kin + (kin >= 64 ? bHi : 0);
      int n = n0 + ngrp * 8;
      const fp16* src = B + (long long)slab * bSlab + (long long)col * ldb + n;
      if (kk < K && n + 8 <= Ncols) {
        f16x8 v = *(const f16x8*)src;
#pragma unroll
        for (int j = 0; j < 8; ++j) Bs[ngrp * 8 + j][tid & 31] = v[j];
      } else {
#pragma unroll
        for (int j = 0; j < 8; ++j)
          Bs[ngrp * 8 + j][tid & 31] = (kk < K && n + j < Ncols) ? src[j] : (fp16)0.f;
      }
    }
    __syncthreads();
    f16x8 af[WM], bf[2];
#pragma unroll
    for (int wm = 0; wm < WM; ++wm)
      af[wm] = *(const f16x8*)&As[wr * (MT / 2) + wm * 16 + ln][quad * 8];
#pragma unroll
    for (int wn = 0; wn < 2; ++wn)
      bf[wn] = *(const f16x8*)&Bs[wc * 32 + wn * 16 + ln][quad * 8];
#pragma unroll
    for (int wm = 0; wm < WM; ++wm)
#pragma unroll
      for (int wn = 0; wn < 2; ++wn)
        acc[wm][wn] =
            __builtin_amdgcn_mfma_f32_16x16x32_f16(af[wm], bf[wn], acc[wm][wn], 0, 0, 0);
    __syncthreads();
  }
#pragma unroll
  for (int wm = 0; wm < WM; ++wm) {
#pragma unroll
    for (int wn = 0; wn < 2; ++wn) {
#pragma unroll
      for (int r = 0; r < 4; ++r) {
        int gm = gm0 + wr * (MT / 2) + wm * 16 + quad * 4 + r;
        int gn = n0 + wc * 32 + wn * 16 + ln;
        if (gm < M && gn < Ncols) {
          float v = alpha * acc[wm][wn][r];
          if (bias) v += BIASROW ? bias[gm] : bias[(long long)z * biasBatch + gn];
          if (S2) v += S2[(long long)gm * 64 + gn];
          long long ci = TRANSC ? ((long long)gn * ldc + gm) : ((long long)gm * ldc + gn);
          if (S) v += beta * ldf(S[ci]);
          if (act == 1) v = fmaxf(v, 0.f);
          else if (act == 2) v = 1.f / (1.f + expf(-v));
          else if (act == 3) v = tanhf(v);
          stf(&C[ci], v);
        }
      }
    }
  }
}

// ---------- ConvLSTM conv as MFMA ----------
__global__ __launch_bounds__(256) void k_conv_mfma(
    const fp16* __restrict__ Zf, const fp16* __restrict__ h,
    const fp16* __restrict__ wcat, fp16* __restrict__ gates, int p) {
  __shared__ fp16 As[128][40];
  __shared__ fp16 Bs[64][40];
  const int gm0 = blockIdx.x * 128, n0 = blockIdx.y * 64;
  const int tid = threadIdx.x;
  const int lane = tid & 63, wv = tid >> 6;
  const int wr = wv >> 1, wc = wv & 1;
  const int quad = lane >> 4, ln = lane & 15;
  f32x4 acc[4][2];
#pragma unroll
  for (int i = 0; i < 4; ++i)
#pragma unroll
    for (int j = 0; j < 2; ++j) acc[i][j] = (f32x4){0.f, 0.f, 0.f, 0.f};

  for (int kb = 0; kb < 36; ++kb) {
    const int srcsel = kb >= 18;
    const int tap = (kb >> 1) % 9;
    const int half = kb & 1;
    const int dy = tap / 3 - 1, dx = tap % 3 - 1;
#pragma unroll
    for (int i = 0; i < 2; ++i) {
      int c = tid + 256 * i;
      int row = c >> 2, seg = c & 3;
      int m = gm0 + row;
      int b = m >> 10;
      int y = (m >> 5) & 31, x = m & 31;
      int yy = y + dy, xx = x + dx;
      bool valid = ((unsigned)yy < 32u) && ((unsigned)xx < 32u);
      f16x8 v;
      if (valid) {
        long long cell = ((long long)b << 10) + (yy << 5) + xx;
        const fp16* sp =
            srcsel ? (h + cell * 64)
                   : (Zf + ((((long long)(b * PP + p)) << 10) + (yy << 5) + xx) * 64);
        v = *(const f16x8*)(sp + half * 32 + seg * 8);
      } else {
#pragma unroll
        for (int j = 0; j < 8; ++j) v[j] = (fp16)0.f;
      }
      *(f16x8*)&As[row][seg * 8] = v;
    }
    {
      int kk = kb * 32 + (tid & 31);
      int ngrp = tid >> 5;
      int n = n0 + ngrp * 8;
      f16x8 v = *(const f16x8*)(wcat + (long long)kk * 256 + n);
#pragma unroll
      for (int j = 0; j < 8; ++j) Bs[ngrp * 8 + j][tid & 31] = v[j];
    }
    __syncthreads();
    f16x8 af[4], bf[2];
#pragma unroll
    for (int wm = 0; wm < 4; ++wm)
      af[wm] = *(const f16x8*)&As[wr * 64 + wm * 16 + ln][quad * 8];
#pragma unroll
    for (int wn = 0; wn < 2; ++wn)
      bf[wn] = *(const f16x8*)&Bs[wc * 32 + wn * 16 + ln][quad * 8];
#pragma unroll
    for (int wm = 0; wm < 4; ++wm)
#pragma unroll
      for (int wn = 0; wn < 2; ++wn)
        acc[wm][wn] =
            __builtin_amdgcn_mfma_f32_16x16x32_f16(af[wm], bf[wn], acc[wm][wn], 0, 0, 0);
    __syncthreads();
  }
#pragma unroll
  for (int wm = 0; wm < 4; ++wm)
#pragma unroll
    for (int wn = 0; wn < 2; ++wn)
#pragma unroll
      for (int r = 0; r < 4; ++r) {
        int gm = gm0 + wr * 64 + wm * 16 + quad * 4 + r;
        int gn = n0 + wc * 32 + wn * 16 + ln;
        gates[(long long)gm * 256 + gn] = (fp16)acc[wm][wn][r];
      }
}

__global__ void k_clstm_update(const fp16* __restrict__ gates, float* __restrict__ c,
                               fp16* __restrict__ h, fp16* __restrict__ Zc, int p) {
  long long i = (long long)blockIdx.x * 256 + threadIdx.x;
  if (i >= (long long)BB * CC * 64) return;
  int d = (int)(i & 63);
  long long bc = i >> 6;
  int b = (int)(bc >> 10);
  int cell = (int)(bc & 1023);
  const fp16* g = gates + (((long long)b * CC) + cell) * 256;
  float gi = (float)g[d], gf = (float)g[64 + d], gg = (float)g[128 + d],
        go = (float)g[192 + d];
  float hs_f = fminf(fmaxf(0.2f * gf + 0.5f, 0.f), 1.f);
  float hs_i = fminf(fmaxf(0.2f * gi + 0.5f, 0.f), 1.f);
  float hs_o = fminf(fmaxf(0.2f * go + 0.5f, 0.f), 1.f);
  float cv = hs_f * c[i] + hs_i * tanhf(gg);
  c[i] = cv;
  float hv = hs_o * tanhf(cv);
  h[i] = (fp16)hv;
  Zc[(((long long)(b * PP + p)) * CC + cell) * 64 + d] = (fp16)hv;
}

// ---------- Xf pieces ----------
// Tmat[row][j] = relu(X[row]*w1[j]+b1[j]) fp16
__global__ void k_tmat(const float* __restrict__ X, const float* __restrict__ w1,
                       const float* __restrict__ b1, fp16* __restrict__ T) {
  long long i = (long long)blockIdx.x * 256 + threadIdx.x;
  if (i >= (long long)BB * PP * NN * 64) return;
  int j = (int)(i & 63);
  long long row = i >> 6;
  T[i] = (fp16)fmaxf(X[row] * w1[j] + b1[j], 0.f);
}

// ---------- DCGRU transposed elementwise ----------
// Ut0[b][c][n]: c<64 from ZXt[bp], 64..127 from hgT
__global__ void k_u0T(const fp16* __restrict__ ZXt, const float* __restrict__ hgT,
                      fp16* __restrict__ U0, int p) {
  long long i = (long long)blockIdx.x * 256 + threadIdx.x;
  if (i >= (long long)BB * 128 * NN) return;
  int n = (int)(i % NN);
  int c = (int)((i / NN) & 127);
  int b = (int)(i / (NN * 128));
  fp16 v;
  if (c < 64)
    v = ZXt[(((long long)(b * PP + p)) * 64 + c) * NN + n];
  else
    v = (fp16)hgT[(long long)(c - 64) * (BB * NN) + b * NN + n];
  U0[((long long)b * 192 + c) * NN + n] = v;
}

__global__ void k_u0cT(const float* __restrict__ ruT, const float* __restrict__ hgT,
                       fp16* __restrict__ U0) {
  long long i = (long long)blockIdx.x * 256 + threadIdx.x;
  if (i >= (long long)BB * 64 * NN) return;
  int n = (int)(i % NN);
  int d = (int)((i / NN) & 63);
  int b = (int)(i / (NN * 64));
  float r = ruT[((long long)b * 128 + d) * NN + n];
  float h = hgT[(long long)d * (BB * NN) + b * NN + n];
  U0[((long long)b * 192 + 128 + d) * NN + n] = (fp16)(r * h);
}

__global__ void k_h_updT(float* __restrict__ hgT, const float* __restrict__ ruT,
                         const float* __restrict__ cndT) {
  long long i = (long long)blockIdx.x * 256 + threadIdx.x;
  if (i >= (long long)BB * 64 * NN) return;
  int n = (int)(i % NN);
  int d = (int)((i / NN) & 63);
  int b = (int)(i / (NN * 64));
  float u = ruT[((long long)b * 128 + 64 + d) * NN + n];
  long long hi = (long long)d * (BB * NN) + b * NN + n;
  float cn = cndT[((long long)b * 64 + d) * NN + n];
  hgT[hi] = u * hgT[hi] + (1.f - u) * cn;
}

__global__ void k_trT(const float* __restrict__ hgT, float* __restrict__ htmp) {
  long long i = (long long)blockIdx.x * 256 + threadIdx.x;
  if (i >= (long long)BB * NN * 64) return;
  int d = (int)(i & 63);
  long long bn = i >> 6;
  htmp[i] = hgT[(long long)d * (BB * NN) + bn];
}

__global__ void k_out(const float* __restrict__ Y, float* __restrict__ out) {
  int i = blockIdx.x * 256 + threadIdx.x;
  if (i >= BB * QQ * NN) return;
  int n = i % NN;
  int bq = i / NN;
  int b = bq / QQ, q = bq % QQ;
  out[i] = Y[((long long)b * NN + n) * 12 + q];
}

// ---------- host helpers ----------
template <typename TA, typename TB, typename TC>
static void launch_gemm(hipStream_t stream, const TA* A, int lda, long long sA,
                        const TB* Bm, int ldb, long long sB, TC* Cm, int ldc, long long sC,
                        const TC* S, long long sS, const float* bias, int M, int Nc, int K,
                        float alpha, float beta, int act, int batch) {
  dim3 g((M + 63) / 64, (Nc + 63) / 64, batch);
  gemm_t<TA, TB, TC><<<g, dim3(256), 0, stream>>>(A, lda, sA, Bm, ldb, sB, Cm, ldc, sC, S,
                                                  sS, bias, M, Nc, K, alpha, beta, act);
}

extern "C" void kernel_launch(void* const* d_in, const int* in_sizes, int n_in,
                              void* d_out, int out_size, void* d_ws, size_t ws_size,
                              hipStream_t stream) {
  char* base = (char*)d_ws;
  size_t off = 0;
  auto alloc_bytes = [&](size_t nb) -> char* {
    char* p = base + off;
    off += (nb + 255) & ~(size_t)255;
    return p;
  };
  auto allocf = [&](size_t n) -> float* { return (float*)alloc_bytes(n * 4); };
  auto alloch = [&](size_t n) -> fp16* { return (fp16*)alloc_bytes(n * 2); };

  const float* X = (const float*)d_in[0];
  const float* Z = (const float*)d_in[1];
  const int* TE = (const int*)d_in[2];
  const float* adj_gg = (const float*)d_in[3];
  const float* adj_gr = (const float*)d_in[4];
  const float* gumbel = (const float*)d_in[5];
  const float* se_x = (const float*)d_in[6];
  const float* se_z = (const float*)d_in[7];
  const float* movement = (const float*)d_in[8];
  auto W = [&](int i) { return (const float*)d_in[i]; };

  // ---- allocations ----
  fp16* wcat = alloch(1152 * 256);
  fp16* gwT = alloch(128 * 512);
  fp16* cwT = alloch(64 * 512);
  fp16* w2T = alloch(64 * 64);
  float* dinv = allocf(NN);
  fp16* Lh = alloch((size_t)NN * NN);
  fp16* mZh = alloch((size_t)CC * CC);
  fp16* agh = alloch((size_t)NN * CC);
  float* seZ = allocf(CC * 64);
  float* teZ = allocf(BB * PP * 64);
  float* seX = allocf(NN * 64);
  float* teXb = allocf(BB * PP * 64);
  float* mtmp = allocf(NN * 64);
  float* tetmp = allocf(BB * PP * 64);
  float* hgT = allocf((size_t)64 * BB * NN);          // [64 d][b*2000+n]
  float* ruT = allocf((size_t)BB * 128 * NN);         // [b][128][2000]
  float* cndT = allocf((size_t)BB * 64 * NN);         // [b][64][2000]
  // U slabs: 4 terms x [16 b][192 col][2000 node] fp16 (49.15 MB total)
  // aliases: ConvLSTM {gates,chh,ccc}; Tmat (384000x64 fp16); htmp (f32)
  const long long SLAB = (long long)BB * 192 * NN;    // 6,144,000 elem
  fp16* Uall = alloch((size_t)4 * SLAB);
  fp16* gates = (fp16*)Uall;
  fp16* chh = (fp16*)((char*)Uall + 8388608);
  float* ccc = (float*)((char*)Uall + 12582912);
  fp16* Tmat = (fp16*)Uall;                           // 49.15 MB exactly fits
  float* htmp = (float*)Uall;                         // 8.2 MB
  // zpool: Zf (B,P,C,64) then ZXt [bp][64][2000] (same size)
  fp16* zpool = alloch((size_t)BB * PP * NN * 64);
  fp16* Zf = zpool;
  fp16* ZXt = zpool;
  fp16* Zc = alloch((size_t)BB * PP * CC * 64);

  if (off > ws_size) return;  // soft-fail diagnostic

  // ---- precompute ----
  k_f2h<<<dim3(576), dim3(256), 0, stream>>>(wcat, W(39), 576 * 256);
  k_f2h<<<dim3(576), dim3(256), 0, stream>>>(wcat + 576 * 256, W(40), 576 * 256);
  k_gru_repackT<<<dim3(256), dim3(256), 0, stream>>>(gwT, W(41), 128);
  k_gru_repackT<<<dim3(128), dim3(256), 0, stream>>>(cwT, W(43), 64);
  k_w2T<<<dim3(16), dim3(256), 0, stream>>>(w2T, W(31));
  k_dinv<<<dim3(NN), dim3(256), 0, stream>>>(adj_gg, dinv);
  k_L<<<dim3((NN * NN + 255) / 256), dim3(256), 0, stream>>>(adj_gg, dinv, Lh);
  k_gumbel_softmax<<<dim3(CC), dim3(256), 0, stream>>>(movement, gumbel, mZh);
  k_f2h<<<dim3((NN * CC + 255) / 256), dim3(256), 0, stream>>>(agh, adj_gr,
                                                               (long long)NN * CC);

  // ---- STEZ ----
  launch_gemm(stream, se_z, 64, 0LL, W(17), 64, 0LL, mtmp, 64, 0LL, (float*)nullptr, 0LL,
              W(18), CC, 64, 64, 1.f, 0.f, 1, 1);
  launch_gemm(stream, (const float*)mtmp, 64, 0LL, W(19), 64, 0LL, seZ, 64, 0LL,
              (float*)nullptr, 0LL, W(20), CC, 64, 64, 1.f, 0.f, 0, 1);
  k_te<<<dim3((BB * PP * 64 + 255) / 256), dim3(256), 0, stream>>>(TE, W(21), W(22), tetmp);
  launch_gemm(stream, (const float*)tetmp, 64, 0LL, W(23), 64, 0LL, teZ, 64, 0LL,
              (float*)nullptr, 0LL, W(24), BB * PP, 64, 64, 1.f, 0.f, 0, 1);

  // ---- STEX (needed by agh epilogue) ----
  launch_gemm(stream, se_x, 64, 0LL, W(9), 64, 0LL, mtmp, 64, 0LL, (float*)nullptr, 0LL,
              W(10), NN, 64, 64, 1.f, 0.f, 1, 1);
  launch_gemm(stream, (const float*)mtmp, 64, 0LL, W(11), 64, 0LL, seX, 64, 0LL,
              (float*)nullptr, 0LL, W(12), NN, 64, 64, 1.f, 0.f, 0, 1);
  k_te<<<dim3((BB * PP * 64 + 255) / 256), dim3(256), 0, stream>>>(TE, W(13), W(14), tetmp);
  launch_gemm(stream, (const float*)tetmp, 64, 0LL, W(15), 64, 0LL, teXb, 64, 0LL,
              (float*)nullptr, 0LL, W(16), BB * PP, 64, 64, 1.f, 0.f, 0, 1);
  k_addb<<<dim3((BB * PP * 64 + 255) / 256), dim3(256), 0, stream>>>(teXb, W(32),
                                                                     BB * PP * 64);

  // ---- Zf = mlp2(Z) + STEZ ----
  long long nZ = (long long)BB * PP * CC * 64;
  k_zf1<<<dim3((int)((nZ + 255) / 256)), dim3(256), 0, stream>>>(Z, W(25), W(26), Zc);
  launch_gemm(stream, (const fp16*)Zc, 64, 0LL, W(27), 64, 0LL, Zf, 64, 0LL,
              (fp16*)nullptr, 0LL, W(28), BB * PP * CC, 64, 64, 1.f, 0.f, 0, 1);
  k_add_stez<<<dim3((int)((nZ + 255) / 256)), dim3(256), 0, stream>>>(Zf, seZ, teZ);

  // ---- ConvLSTM ----
  hipMemsetAsync(chh, 0, (size_t)BB * CC * 64 * 2, stream);
  hipMemsetAsync(ccc, 0, (size_t)BB * CC * 64 * 4, stream);
  for (int p = 0; p < PP; ++p) {
    k_conv_mfma<<<dim3(BB * CC / 128, 4), dim3(256), 0, stream>>>(Zf, chh, wcat, gates, p);
    k_clstm_update<<<dim3((int)(((long long)BB * CC * 64 + 255) / 256)), dim3(256), 0,
                     stream>>>(gates, ccc, chh, Zc, p);
  }

  // ---- movement: Zf <- mZ@Zc ; Zc <- relu(Zf@W+b) ; ZXt <- (agh@Zc)^T + seX + teXb ----
  mfma2<fp16, 128, false, false, false><<<dim3(8, 1, 192), dim3(256), 0, stream>>>(
      mZh, CC, 0LL, (const fp16*)Zc, 64, (long long)CC * 64, 31, 0LL, 0, Zf, 64,
      (long long)CC * 64, (const fp16*)nullptr, 0.f, nullptr, 0, nullptr, CC, 64, CC, 1.f,
      0);
  launch_gemm(stream, (const fp16*)Zf, 64, 0LL, W(33), 64, 0LL, Zc, 64, 0LL,
              (fp16*)nullptr, 0LL, W(34), BB * PP * CC, 64, 64, 1.f, 0.f, 1, 1);
  mfma2<fp16, 128, false, true, false><<<dim3(16, 1, 192), dim3(256), 0, stream>>>(
      agh, CC, 0LL, (const fp16*)Zc, 64, (long long)CC * 64, 31, 0LL, 0, ZXt, NN,
      (long long)64 * NN, (const fp16*)nullptr, 0.f, teXb, 64, seX, NN, 64, CC, 1.f, 0);

  // ---- ZXt += (relu(X*w1+b1) @ w2)^T  via w2T @ Tmat^T ----
  k_tmat<<<dim3((int)(((long long)BB * PP * NN * 64 + 255) / 256)), dim3(256), 0, stream>>>(
      X, W(29), W(30), Tmat);
  mfma2<fp16, 64, true, false, false><<<dim3(1, 32, 192), dim3(256), 0, stream>>>(
      w2T, 64, 0LL, Tmat, 64, (long long)NN * 64, 31, 0LL, 0, ZXt, NN, (long long)64 * NN,
      (const fp16*)ZXt, 1.f, nullptr, 0, nullptr, 64, NN, 64, 1.f, 0);

  // ---- DCGRU (transposed chain; L symmetric so T^T_{k+1} = T^T_k @ L) ----
  hipMemsetAsync(hgT, 0, (size_t)64 * BB * NN * 4, stream);
  fp16* U0 = Uall;
  fp16* U1 = Uall + SLAB;
  fp16* U2 = Uall + 2 * SLAB;
  fp16* U3 = Uall + 3 * SLAB;
  const long long uB = (long long)192 * NN;  // per-b stride inside a slab
  const long long n128 = (long long)BB * 128 * NN;
  const long long n64 = (long long)BB * 64 * NN;
  for (int p = 0; p < PP; ++p) {
    // gate chain, Ut rows 0..127 = [x|h]
    k_u0T<<<dim3((int)((n128 + 255) / 256)), dim3(256), 0, stream>>>(ZXt, hgT, U0, p);
    mfma2<fp16, 128, true, false, false><<<dim3(1, 32, BB), dim3(256), 0, stream>>>(
        U0, NN, uB, Lh, NN, 0LL, 31, 0LL, 0, U1, NN, uB, (const fp16*)nullptr, 0.f,
        nullptr, 0, nullptr, 128, NN, NN, 1.f, 0);
    mfma2<fp16, 128, true, false, false><<<dim3(1, 32, BB), dim3(256), 0, stream>>>(
        U1, NN, uB, Lh, NN, 0LL, 31, 0LL, 0, U2, NN, uB, (const fp16*)U0, -1.f, nullptr, 0,
        nullptr, 128, NN, NN, 2.f, 0);
    mfma2<fp16, 128, true, false, false><<<dim3(1, 32, BB), dim3(256), 0, stream>>>(
        U2, NN, uB, Lh, NN, 0LL, 31, 0LL, 0, U3, NN, uB, (const fp16*)U1, -1.f, nullptr, 0,
        nullptr, 128, NN, NN, 2.f, 0);
    // ruT = sigmoid(gwT @ U^T): K=512 over 4 slabs, cols 0..127
    mfma2<float, 128, false, false, true><<<dim3(1, 32, BB), dim3(256), 0, stream>>>(
        gwT, 512, 0LL, Uall, NN, uB, 7, SLAB, 0, ruT, NN, (long long)128 * NN,
        (const float*)nullptr, 0.f, W(42), 0, nullptr, 128, NN, 512, 1.f, 2);
    // cand chain, Ut rows 128..191 = r*h
    k_u0cT<<<dim3((int)((n64 + 255) / 256)), dim3(256), 0, stream>>>(ruT, hgT, U0);
    mfma2<fp16, 64, true, false, false><<<dim3(1, 32, BB), dim3(256), 0, stream>>>(
        U0 + 128 * NN, NN, uB, Lh, NN, 0LL, 31, 0LL, 0, U1 + 128 * NN, NN, uB,
        (const fp16*)nullptr, 0.f, nullptr, 0, nullptr, 64, NN, NN, 1.f, 0);
    mfma2<fp16, 64, true, false, false><<<dim3(1, 32, BB), dim3(256), 0, stream>>>(
        U1 + 128 * NN, NN, uB, Lh, NN, 0LL, 31, 0LL, 0, U2 + 128 * NN, NN, uB,
        (const fp16*)(U0 + 128 * NN), -1.f, nullptr, 0, nullptr, 64, NN, NN, 2.f, 0);
    mfma2<fp16, 64, true, false, false><<<dim3(1, 32, BB), dim3(256), 0, stream>>>(
        U2 + 128 * NN, NN, uB, Lh, NN, 0LL, 31, 0LL, 0, U3 + 128 * NN, NN, uB,
        (const fp16*)(U1 + 128 * NN), -1.f, nullptr, 0, nullptr, 64, NN, NN, 2.f, 0);
    // cndT = tanh(cwT @ U^T): K=512, cols [x: 0..63 | rh: 128..191] via bHi=64
    mfma2<float, 64, false, false, true><<<dim3(1, 32, BB), dim3(256), 0, stream>>>(
        cwT, 512, 0LL, Uall, NN, uB, 7, SLAB, 64, cndT, NN, (long long)64 * NN,
        (const float*)nullptr, 0.f, W(44), 0, nullptr, 64, NN, 512, 1.f, 3);
    k_h_updT<<<dim3((int)((n64 + 255) / 256)), dim3(256), 0, stream>>>(hgT, ruT, cndT);
  }

  // ---- output head ----
  k_trT<<<dim3((int)(((long long)BB * NN * 64 + 255) / 256)), dim3(256), 0, stream>>>(hgT,
                                                                                      htmp);
  launch_gemm(stream, (const float*)htmp, 64, 0LL, W(35), 64, 0LL, (float*)cndT, 64, 0LL,
              (float*)nullptr, 0LL, W(36), BB * NN, 64, 64, 1.f, 0.f, 1, 1);
  launch_gemm(stream, (const float*)cndT, 64, 0LL, W(37), 12, 0LL, (float*)ruT, 12, 0LL,
              (float*)nullptr, 0LL, W(38), BB * NN, 12, 64, 1.f, 0.f, 0, 1);
  k_out<<<dim3((BB * QQ * NN + 255) / 256), dim3(256), 0, stream>>>((const float*)ruT,
                                                                    (float*)d_out);
}